// Round 1
// 324.722 us; speedup vs baseline: 1.0952x; 1.0952x over previous
//
#include <hip/hip_runtime.h>
#include <hip/hip_bf16.h>
#include <math.h>

#define HIDDEN 1280
#define HEADS 16
#define HD 80           // head dim
#define HALF 40
#define BB 2
#define NN 2048
#define MROWS (BB * NN) // 4096
// 1/sqrt(80) * log2(e): scores come out in log2 domain -> exp2 directly
#define QSCALE ((float)(0.11180339887498949 * 1.4426950408889634))

typedef __attribute__((ext_vector_type(8))) _Float16 f16x8;
typedef __attribute__((ext_vector_type(4))) float f32x4;

#define AS1 __attribute__((address_space(1)))
#define AS3 __attribute__((address_space(3)))

// Split fp32 into fp16 hi + fp16 lo (hi+lo carries ~22 mantissa bits).
__device__ __forceinline__ void splitf16(float x, ushort& hi, ushort& lo) {
    _Float16 h = (_Float16)x;
    _Float16 l = (_Float16)(x - (float)h);
    hi = __builtin_bit_cast(ushort, h);
    lo = __builtin_bit_cast(ushort, l);
}

__device__ __forceinline__ ushort f2h(float x) {
    _Float16 h = (_Float16)x;
    return __builtin_bit_cast(ushort, h);
}

// ---------------------------------------------------------------------------
// Elementwise split: fp32 [n] -> fp16 hi[n], lo[n]. 4 elems/thread.
// ---------------------------------------------------------------------------
__global__ __launch_bounds__(256) void split_f16_kernel(
    const float* __restrict__ in, ushort* __restrict__ hi,
    ushort* __restrict__ lo, int n4)
{
    int i = blockIdx.x * 256 + threadIdx.x;
    if (i >= n4) return;
    float4 v = ((const float4*)in)[i];
    ushort4 h, l;
    splitf16(v.x, h.x, l.x);
    splitf16(v.y, h.y, l.y);
    splitf16(v.z, h.z, l.z);
    splitf16(v.w, h.w, l.w);
    ((ushort4*)hi)[i] = h;
    ((ushort4*)lo)[i] = l;
}

// ---------------------------------------------------------------------------
// Transpose to fp16: W[K][N] fp32 -> WT[N][K] fp16 (single plane).
// ---------------------------------------------------------------------------
__global__ __launch_bounds__(256) void tsplit_f16_kernel(
    const float* __restrict__ W, ushort* __restrict__ T, int K, int N)
{
    __shared__ float s[32][33];
    const int n0 = blockIdx.x * 32;
    const int k0 = blockIdx.y * 32;
    {
        int tn = threadIdx.x & 31, tk = threadIdx.x >> 5;
        #pragma unroll
        for (int i = 0; i < 4; ++i)
            s[tk + i * 8][tn] = W[(size_t)(k0 + tk + i * 8) * N + n0 + tn];
    }
    __syncthreads();
    {
        int tk = threadIdx.x & 31, tn = threadIdx.x >> 5;
        #pragma unroll
        for (int i = 0; i < 4; ++i)
            T[(size_t)(n0 + tn + i * 8) * K + k0 + tk] = f2h(s[tk][tn + i * 8]);
    }
}

// ---------------------------------------------------------------------------
// fp16x2 MFMA GEMM (128x128, 2-barrier structure) — kept for the proj GEMM
// (N=1280: 320 wgs here vs only 80 wgs at 256^2 tiles).
// ---------------------------------------------------------------------------
#define BM 128
#define BN 128
#define BK 32

__global__ __launch_bounds__(256) void gemm_f16x2_kernel(
    const ushort* __restrict__ Ahi, const ushort* __restrict__ Alo,
    const ushort* __restrict__ Bh,
    const float* __restrict__ bias, float* __restrict__ C,
    int M, int N, int K)
{
    __shared__ __align__(16) ushort lds[3 * 128 * 32];   // 24 KB

    const int tid = threadIdx.x;
    const int wid = tid >> 6;
    const int lane = tid & 63;
    const int col0 = blockIdx.x * BN;
    const int row0 = blockIdx.y * BM;
    const int wy = wid >> 1, wx = wid & 1;
    const int lrow = lane >> 2;
    const int lchunk = lane & 3;

    f32x4 acc[4][4] = {};

    for (int k0 = 0; k0 < K; k0 += BK) {
        __syncthreads();
        // 24 segments (3 tiles x 8), 6 per wave
        #pragma unroll
        for (int i = 0; i < 6; ++i) {
            int s = wid + i * 4;
            int tile = s >> 3, t = s & 7;
            const ushort* src = (tile == 0) ? Ahi : (tile == 1) ? Alo : Bh;
            int srow = (tile < 2) ? row0 : col0;
            const ushort* g = src + (size_t)(srow + t * 16 + lrow) * K + k0 + lchunk * 8;
            ushort* l = lds + tile * 4096 + t * 512 + lane * 8;
            __builtin_amdgcn_global_load_lds(
                (const AS1 unsigned int*)g, (AS3 unsigned int*)l, 16, 0, 0);
        }
        __syncthreads();

        const int q = lane >> 4;
        const int r = lane & 15;
        f16x8 ah[4], al[4], bf[4];
        #pragma unroll
        for (int i = 0; i < 4; ++i) {
            int arow = wy * 64 + i * 16 + r;
            ah[i] = *(const f16x8*)(lds + 0 * 4096 + arow * 32 + q * 8);
            al[i] = *(const f16x8*)(lds + 1 * 4096 + arow * 32 + q * 8);
            int brow = wx * 64 + i * 16 + r;
            bf[i] = *(const f16x8*)(lds + 2 * 4096 + brow * 32 + q * 8);
        }
        #pragma unroll
        for (int i = 0; i < 4; ++i) {
            #pragma unroll
            for (int j = 0; j < 4; ++j) {
                acc[i][j] = __builtin_amdgcn_mfma_f32_16x16x32_f16(al[i], bf[j], acc[i][j], 0, 0, 0);
                acc[i][j] = __builtin_amdgcn_mfma_f32_16x16x32_f16(ah[i], bf[j], acc[i][j], 0, 0, 0);
            }
        }
    }

    const int q = lane >> 4, r = lane & 15;
    #pragma unroll
    for (int i = 0; i < 4; ++i) {
        #pragma unroll
        for (int j = 0; j < 4; ++j) {
            int col = col0 + wx * 64 + j * 16 + r;
            float b = bias[col];
            #pragma unroll
            for (int v = 0; v < 4; ++v) {
                int row = row0 + wy * 64 + i * 16 + q * 4 + v;
                C[(size_t)row * N + col] = acc[i][j][v] + b;
            }
        }
    }
}

// ---------------------------------------------------------------------------
// 256x256 8-wave deep-pipelined fp16x2 GEMM (new, for the QKV GEMM).
//   C[M,N] = (Ahi+Alo)[M,K] @ B[N,K]^T + bias[N]
// Structure (T3+T4+T2+T5+T1):
//  - 3-buffer LDS ring, 3 planes (Ahi,Alo,B) x [256][32] u16 each = 48 KB/buf,
//    144 KB total. While computing buf[t] (buf[t+1] in flight), the 6 loads
//    for tile t+2 are issued into the buffer last read at t-1 (barrier-safe).
//  - 4 phases per K-tile: {ds_read frags | issue 2 global_load_lds |
//    s_barrier | lgkmcnt(0)+sched_barrier | setprio(1) 16 MFMA setprio(0) |
//    s_barrier}. Single counted s_waitcnt vmcnt(6) per K-tile (never 0 in
//    the main loop) -> 6-12 loads always in flight.
//  - T2 LDS swizzle: 16B slot ^= (row>>1)&3 within each 64 B row. Applied
//    as linear gload_lds dest + inverse-swizzled GLOBAL source + swizzled
//    ds_read (rule #21 both-sides involution). 2-way max bank aliasing.
//  - T1 XCD swizzle (nwg % 8 == 0), row-major so A panels stay L2-resident.
// Accumulation order per acc element identical to gemm_f16x2_kernel
// (al then ah, K-tiles ascending) -> bit-identical numerics.
// ---------------------------------------------------------------------------
__global__ __launch_bounds__(512, 2) void gemm_f16x2_256_kernel(
    const ushort* __restrict__ Ahi, const ushort* __restrict__ Alo,
    const ushort* __restrict__ Bh,
    const float* __restrict__ bias, float* __restrict__ C,
    int M, int N, int K, int nbx)
{
    __shared__ __align__(16) ushort lds[3 * 3 * 8192];   // 144 KB

    const int tid = threadIdx.x;
    const int wid = tid >> 6;
    const int lane = tid & 63;
    const int q = lane >> 4, r = lane & 15;
    const int wr = wid >> 2, wc = wid & 3;

    // T1: XCD-aware block swizzle (valid: grid % 8 == 0)
    int id = blockIdx.x;
    {
        int nwg = gridDim.x;
        if ((nwg & 7) == 0) {
            int c = nwg >> 3;
            id = (id & 7) * c + (id >> 3);
        }
    }
    const int row0 = (id / nbx) * 256;
    const int col0 = (id % nbx) * 256;

    // --- staging addressing: 6 global_load_lds per K-tile per wave ---
    // instr j: plane pj=j>>1 (0=Ahi,1=Alo,2=B), rows [wid*32+(j&1)*16, +16).
    // LDS dest is LINEAR (base + lane*16); global source pre-swizzled so that
    // LDS(row, slot) holds global slot (slot ^ ((row>>1)&3)).
    const ushort* gsrc[6];
    int ldst[6];
    #pragma unroll
    for (int j = 0; j < 6; ++j) {
        int pj = j >> 1;
        int rloc = wid * 32 + (j & 1) * 16 + (lane >> 2);
        int sl = (lane & 3) ^ ((rloc >> 1) & 3);
        const ushort* base = (pj == 0) ? Ahi : (pj == 1) ? Alo : Bh;
        int grow = ((pj < 2) ? row0 : col0) + rloc;
        gsrc[j] = base + (size_t)grow * K + sl * 8;
        ldst[j] = pj * 8192 + (wid * 32 + (j & 1) * 16) * 32 + lane * 8;
    }

    const int NT = K / 32;

    // prologue: stage tile 0 -> buf0, tile 1 -> buf1
    #pragma unroll
    for (int j = 0; j < 6; ++j)
        __builtin_amdgcn_global_load_lds((const AS1 unsigned int*)(gsrc[j]),
            (AS3 unsigned int*)(lds + ldst[j]), 16, 0, 0);
    #pragma unroll
    for (int j = 0; j < 6; ++j)
        __builtin_amdgcn_global_load_lds((const AS1 unsigned int*)(gsrc[j] + 32),
            (AS3 unsigned int*)(lds + 24576 + ldst[j]), 16, 0, 0);
    asm volatile("s_waitcnt vmcnt(6)" ::: "memory");   // tile 0 landed, tile 1 in flight
    __builtin_amdgcn_s_barrier();

    // per-lane swizzled 16B-slot offset for fragment ds_reads (wave-uniform
    // in row-base since bases are multiples of 16): sel = (r>>1)&3
    const int soff = (q ^ ((r >> 1) & 3)) * 8;
    const int arow0 = wr * 128 + r;     // + m*16
    const int brow0 = wc * 64 + r;      // + n*16

    f32x4 acc[8][4] = {};
    f16x8 ah[4], al[4], bf[4];

    int cb = 0;          // current buffer (tile t)
    int nb = 49152;      // stage target buffer (tile t+2)

    for (int t = 0; t < NT; ++t) {
        const ushort* A0 = lds + cb;
        const ushort* A1 = lds + cb + 8192;
        const ushort* Bp = lds + cb + 16384;
        ushort* nbuf = lds + nb;
        const bool st = (t + 2 < NT);
        const int ko = (t + 2) * 32;

        // ---- phase 1: quadrant (m0-3, n0-1) ----
        #pragma unroll
        for (int m = 0; m < 4; ++m) {
            int ro = (arow0 + m * 16) * 32 + soff;
            ah[m] = *(const f16x8*)(A0 + ro);
            al[m] = *(const f16x8*)(A1 + ro);
        }
        #pragma unroll
        for (int n = 0; n < 2; ++n)
            bf[n] = *(const f16x8*)(Bp + (brow0 + n * 16) * 32 + soff);
        if (st) {
            __builtin_amdgcn_global_load_lds((const AS1 unsigned int*)(gsrc[0] + ko),
                (AS3 unsigned int*)(nbuf + ldst[0]), 16, 0, 0);
            __builtin_amdgcn_global_load_lds((const AS1 unsigned int*)(gsrc[1] + ko),
                (AS3 unsigned int*)(nbuf + ldst[1]), 16, 0, 0);
        }
        __builtin_amdgcn_s_barrier();
        asm volatile("s_waitcnt lgkmcnt(0)" ::: "memory");
        __builtin_amdgcn_sched_barrier(0);
        __builtin_amdgcn_s_setprio(1);
        #pragma unroll
        for (int m = 0; m < 4; ++m) {
            #pragma unroll
            for (int n = 0; n < 2; ++n) {
                acc[m][n] = __builtin_amdgcn_mfma_f32_16x16x32_f16(al[m], bf[n], acc[m][n], 0, 0, 0);
                acc[m][n] = __builtin_amdgcn_mfma_f32_16x16x32_f16(ah[m], bf[n], acc[m][n], 0, 0, 0);
            }
        }
        __builtin_amdgcn_s_setprio(0);
        __builtin_amdgcn_s_barrier();

        // ---- phase 2: quadrant (m0-3, n2-3) ----
        #pragma unroll
        for (int n = 2; n < 4; ++n)
            bf[n] = *(const f16x8*)(Bp + (brow0 + n * 16) * 32 + soff);
        if (st) {
            __builtin_amdgcn_global_load_lds((const AS1 unsigned int*)(gsrc[2] + ko),
                (AS3 unsigned int*)(nbuf + ldst[2]), 16, 0, 0);
            __builtin_amdgcn_global_load_lds((const AS1 unsigned int*)(gsrc[3] + ko),
                (AS3 unsigned int*)(nbuf + ldst[3]), 16, 0, 0);
        }
        __builtin_amdgcn_s_barrier();
        asm volatile("s_waitcnt lgkmcnt(0)" ::: "memory");
        __builtin_amdgcn_sched_barrier(0);
        __builtin_amdgcn_s_setprio(1);
        #pragma unroll
        for (int m = 0; m < 4; ++m) {
            #pragma unroll
            for (int n = 2; n < 4; ++n) {
                acc[m][n] = __builtin_amdgcn_mfma_f32_16x16x32_f16(al[m], bf[n], acc[m][n], 0, 0, 0);
                acc[m][n] = __builtin_amdgcn_mfma_f32_16x16x32_f16(ah[m], bf[n], acc[m][n], 0, 0, 0);
            }
        }
        __builtin_amdgcn_s_setprio(0);
        __builtin_amdgcn_s_barrier();

        // ---- phase 3: quadrant (m4-7, n2-3) ----
        #pragma unroll
        for (int m = 0; m < 4; ++m) {
            int ro = (arow0 + (m + 4) * 16) * 32 + soff;
            ah[m] = *(const f16x8*)(A0 + ro);
            al[m] = *(const f16x8*)(A1 + ro);
        }
        if (st) {
            __builtin_amdgcn_global_load_lds((const AS1 unsigned int*)(gsrc[4] + ko),
                (AS3 unsigned int*)(nbuf + ldst[4]), 16, 0, 0);
            __builtin_amdgcn_global_load_lds((const AS1 unsigned int*)(gsrc[5] + ko),
                (AS3 unsigned int*)(nbuf + ldst[5]), 16, 0, 0);
        }
        __builtin_amdgcn_s_barrier();
        asm volatile("s_waitcnt lgkmcnt(0)" ::: "memory");
        __builtin_amdgcn_sched_barrier(0);
        __builtin_amdgcn_s_setprio(1);
        #pragma unroll
        for (int m = 0; m < 4; ++m) {
            #pragma unroll
            for (int n = 2; n < 4; ++n) {
                acc[m + 4][n] = __builtin_amdgcn_mfma_f32_16x16x32_f16(al[m], bf[n], acc[m + 4][n], 0, 0, 0);
                acc[m + 4][n] = __builtin_amdgcn_mfma_f32_16x16x32_f16(ah[m], bf[n], acc[m + 4][n], 0, 0, 0);
            }
        }
        __builtin_amdgcn_s_setprio(0);
        __builtin_amdgcn_s_barrier();

        // ---- phase 4: quadrant (m4-7, n0-1), register-only ----
        __builtin_amdgcn_s_setprio(1);
        #pragma unroll
        for (int m = 0; m < 4; ++m) {
            #pragma unroll
            for (int n = 0; n < 2; ++n) {
                acc[m + 4][n] = __builtin_amdgcn_mfma_f32_16x16x32_f16(al[m], bf[n], acc[m + 4][n], 0, 0, 0);
                acc[m + 4][n] = __builtin_amdgcn_mfma_f32_16x16x32_f16(ah[m], bf[n], acc[m + 4][n], 0, 0, 0);
            }
        }
        __builtin_amdgcn_s_setprio(0);
        // counted wait: tile t+1's 6 loads retired, tile t+2's 6 stay in flight
        if (st)
            asm volatile("s_waitcnt vmcnt(6)" ::: "memory");
        else if (t + 1 < NT)
            asm volatile("s_waitcnt vmcnt(0)" ::: "memory");
        __builtin_amdgcn_s_barrier();

        cb += 24576; if (cb == 73728) cb = 0;
        nb += 24576; if (nb == 73728) nb = 0;
    }

    // epilogue: bias + store
    #pragma unroll
    for (int m = 0; m < 8; ++m) {
        #pragma unroll
        for (int n = 0; n < 4; ++n) {
            int col = col0 + wc * 64 + n * 16 + r;
            float b = bias[col];
            #pragma unroll
            for (int v = 0; v < 4; ++v) {
                int row = row0 + wr * 128 + m * 16 + q * 4 + v;
                C[(size_t)row * N + col] = acc[m][n][v] + b;
            }
        }
    }
}

// ---------------------------------------------------------------------------
// RoPE + scale + fp16 convert + head-major relayout.
// Reads qkv fp32 (b,n,3,H,80). Writes:
//   qf [bh][n][96] fp16 (RoPE'd, * QSCALE, d 80..95 zeroed)
//   kf [bh][n][96] fp16 (RoPE'd, d 80..95 zeroed)
//   vt [bh][80][2048] fp16 (V transposed)
// Grid (NN/64, HEADS, BB), 256 threads.
// ---------------------------------------------------------------------------
__global__ __launch_bounds__(256) void rope_split_kernel(
    const float* __restrict__ qkv, const float* __restrict__ cos_t,
    const float* __restrict__ sin_t,
    ushort* __restrict__ qf, ushort* __restrict__ kf,
    ushort* __restrict__ vt)
{
    __shared__ float s_v[64][84];
    const int tid = threadIdx.x;
    const int b = blockIdx.z, h = blockIdx.y;
    const int n0 = blockIdx.x * 64;
    const int bh = b * HEADS + h;

    // V tile -> LDS (coalesced float4 loads)
    #pragma unroll
    for (int i = 0; i < 5; ++i) {
        int u = tid + i * 256;
        int n = u / 20, c = u % 20;
        const float* src = qkv + (size_t)(b * NN + n0 + n) * 3840 + 2 * HIDDEN + h * HD + c * 4;
        *(float4*)(&s_v[n][c * 4]) = *(const float4*)src;
    }

    // q,k RoPE + fp16: 640 units, each = (token n, 4-wide d group in [0,40))
    for (int u = tid; u < 640; u += 256) {
        int n = u / 10, p = u % 10;
        int d = p * 4;
        int ng = n0 + n;
        size_t rowb = (size_t)(b * NN + ng) * 3840;
        float4 c0 = *(const float4*)(cos_t + ng * HD + d);
        float4 c1 = *(const float4*)(cos_t + ng * HD + d + HALF);
        float4 s0 = *(const float4*)(sin_t + ng * HD + d);
        float4 s1 = *(const float4*)(sin_t + ng * HD + d + HALF);
        size_t qo = ((size_t)bh * NN + ng) * 96;
        // q (scaled by QSCALE so scores are in log2 domain)
        {
            float4 x0 = *(const float4*)(qkv + rowb + h * HD + d);
            float4 x1 = *(const float4*)(qkv + rowb + h * HD + d + HALF);
            ushort4 h4a, h4b;
            h4a.x = f2h((x0.x * c0.x - x1.x * s0.x) * QSCALE);
            h4a.y = f2h((x0.y * c0.y - x1.y * s0.y) * QSCALE);
            h4a.z = f2h((x0.z * c0.z - x1.z * s0.z) * QSCALE);
            h4a.w = f2h((x0.w * c0.w - x1.w * s0.w) * QSCALE);
            h4b.x = f2h((x1.x * c1.x + x0.x * s1.x) * QSCALE);
            h4b.y = f2h((x1.y * c1.y + x0.y * s1.y) * QSCALE);
            h4b.z = f2h((x1.z * c1.z + x0.z * s1.z) * QSCALE);
            h4b.w = f2h((x1.w * c1.w + x0.w * s1.w) * QSCALE);
            *(ushort4*)(qf + qo + d) = h4a;
            *(ushort4*)(qf + qo + d + HALF) = h4b;
        }
        // k (unscaled)
        {
            float4 x0 = *(const float4*)(qkv + rowb + HIDDEN + h * HD + d);
            float4 x1 = *(const float4*)(qkv + rowb + HIDDEN + h * HD + d + HALF);
            ushort4 h4a, h4b;
            h4a.x = f2h(x0.x * c0.x - x1.x * s0.x);
            h4a.y = f2h(x0.y * c0.y - x1.y * s0.y);
            h4a.z = f2h(x0.z * c0.z - x1.z * s0.z);
            h4a.w = f2h(x0.w * c0.w - x1.w * s0.w);
            h4b.x = f2h(x1.x * c1.x + x0.x * s1.x);
            h4b.y = f2h(x1.y * c1.y + x0.y * s1.y);
            h4b.z = f2h(x1.z * c1.z + x0.z * s1.z);
            h4b.w = f2h(x1.w * c1.w + x0.w * s1.w);
            *(ushort4*)(kf + qo + d) = h4a;
            *(ushort4*)(kf + qo + d + HALF) = h4b;
        }
    }

    // zero the d=80..95 pad for q and k. 256 units: which(1b) x n(6b) x part(1b)
    {
        int which = tid >> 7;
        int u = tid & 127;
        int n = u >> 1, part = u & 1;
        size_t o = ((size_t)bh * NN + n0 + n) * 96 + 80 + part * 8;
        uint4 z = {0u, 0u, 0u, 0u};
        if (which == 0) *(uint4*)(qf + o) = z;
        else            *(uint4*)(kf + o) = z;
    }
    __syncthreads();

    // V^T write (fp16): unit = (d, 16-token chunk)
    for (int u = tid; u < 320; u += 256) {
        int d = u >> 2, nc = u & 3;
        ushort hs[16];
        #pragma unroll
        for (int kk = 0; kk < 16; ++kk)
            hs[kk] = f2h(s_v[nc * 16 + kk][d]);
        size_t o = ((size_t)bh * HD + d) * NN + n0 + nc * 16;
        uint4 w0, w1;
        w0.x = (uint)hs[0] | ((uint)hs[1] << 16);
        w0.y = (uint)hs[2] | ((uint)hs[3] << 16);
        w0.z = (uint)hs[4] | ((uint)hs[5] << 16);
        w0.w = (uint)hs[6] | ((uint)hs[7] << 16);
        w1.x = (uint)hs[8] | ((uint)hs[9] << 16);
        w1.y = (uint)hs[10] | ((uint)hs[11] << 16);
        w1.z = (uint)hs[12] | ((uint)hs[13] << 16);
        w1.w = (uint)hs[14] | ((uint)hs[15] << 16);
        *(uint4*)(vt + o) = w0;
        *(uint4*)(vt + o + 8) = w1;
    }
}

// ---------------------------------------------------------------------------
// MFMA flash attention v4 (round-7 structure, fp16 single-term QK):
//  - QK^T: 16x16x32 fp16 x1 over 96-wide padded K (QSCALE baked into q).
//  - PV: 16x16x32 fp16 x1 (round-7 validated swizzle pairs).
//  - no-max softmax (exp2, log2-domain scores), deferred l reduction.
//  - LDS 40960 B.
// ---------------------------------------------------------------------------
__global__ __launch_bounds__(256, 2) void attn_mfma_kernel(
    const ushort* __restrict__ qf, const ushort* __restrict__ kf,
    const ushort* __restrict__ vt,
    ushort* __restrict__ ao_hi, ushort* __restrict__ ao_lo)
{
    __shared__ __align__(16) ushort lds[20480];   // 40960 B
    ushort* k_s = lds;                            // [64][96] = 6144
    _Float16* v_s = (_Float16*)(lds + 6144);      // [80][64] chunk-swizzled
    _Float16* p_s = (_Float16*)(lds + 11264);     // [128][64] block-swizzled

    const int tid = threadIdx.x;
    const int wave = tid >> 6, lane = tid & 63;
    const int quad = lane >> 4, r = lane & 15;
    const int b = blockIdx.z, h = blockIdx.y;
    const int bh = b * HEADS + h;
    const int q0 = blockIdx.x * 128;

    // Q a-frags from [bh][n][96] fp16 (pre-scaled by QSCALE, pad zero)
    f16x8 qfr[2][3];
    #pragma unroll
    for (int mt = 0; mt < 2; ++mt)
        #pragma unroll
        for (int c = 0; c < 3; ++c) {
            size_t o = ((size_t)bh * NN + q0 + wave * 32 + mt * 16 + r) * 96 + c * 32 + quad * 8;
            qfr[mt][c] = *(const f16x8*)(qf + o);
        }

    f32x4 oacc[2][5] = {};
    float l_part[2][4] = {};

    const size_t kb = (size_t)bh * NN * 96;
    const size_t vb = (size_t)bh * HD * NN;

    for (int j0 = 0; j0 < NN; j0 += 64) {
        __syncthreads();
        // stage K fp16 (12 segs, linear) + V^T fp16 (10 segs, src-swizzled)
        for (int s = wave; s < 22; s += 4) {
            if (s < 12) {
                int off = s * 512 + lane * 8;
                __builtin_amdgcn_global_load_lds(
                    (const AS1 unsigned int*)(kf + kb + (size_t)j0 * 96 + off),
                    (AS3 unsigned int*)(k_s + off), 16, 0, 0);
            } else {
                int ts = s - 12;
                int off = ts * 512 + lane * 8;
                size_t go = vb + (size_t)(ts * 8 + (lane >> 3)) * NN + j0
                          + (size_t)(((lane & 7) ^ (lane >> 3)) * 8);
                __builtin_amdgcn_global_load_lds(
                    (const AS1 unsigned int*)(vt + go),
                    (AS3 unsigned int*)((ushort*)v_s + off), 16, 0, 0);
            }
        }
        __syncthreads();

        // QK^T -> scores in C-layout (log2 domain), single fp16 term
        f32x4 sc[2][4] = {};
        #pragma unroll
        for (int jt = 0; jt < 4; ++jt) {
            f16x8 kbf[3];
            int j = jt * 16 + r;
            #pragma unroll
            for (int c = 0; c < 3; ++c)
                kbf[c] = *(const f16x8*)(k_s + j * 96 + c * 32 + quad * 8);
            #pragma unroll
            for (int mt = 0; mt < 2; ++mt)
                #pragma unroll
                for (int c = 0; c < 3; ++c)
                    sc[mt][jt] = __builtin_amdgcn_mfma_f32_16x16x32_f16(qfr[mt][c], kbf[c], sc[mt][jt], 0, 0, 0);
        }

        // no-max softmax: p = exp2(s); P -> LDS fp16 (swizzled); l partials
        #pragma unroll
        for (int mt = 0; mt < 2; ++mt) {
            #pragma unroll
            for (int v = 0; v < 4; ++v) {
                float ps = 0.0f;
                #pragma unroll
                for (int jt = 0; jt < 4; ++jt) {
                    float p = __builtin_amdgcn_exp2f(sc[mt][jt][v]);
                    sc[mt][jt][v] = p;
                    ps += p;
                }
                l_part[mt][v] += ps;
            }
            int rowbase = wave * 32 + mt * 16 + quad * 4;
            #pragma unroll
            for (int jt = 0; jt < 4; ++jt) {
                int bks = (jt * 2 + (r >> 3)) ^ (quad << 1);
                #pragma unroll
                for (int v = 0; v < 4; ++v)
                    p_s[(rowbase + v) * 64 + bks * 8 + (r & 7)] = (_Float16)sc[mt][jt][v];
            }
        }

        // P a-frags (wave-private rows, swizzled reads — round-7 pair)
        f16x8 pa[2][2];
        #pragma unroll
        for (int mt = 0; mt < 2; ++mt)
            #pragma unroll
            for (int cc = 0; cc < 2; ++cc) {
                int rowp = wave * 32 + mt * 16 + r;
                int bks = (cc * 4 + quad) ^ (((r >> 2) & 3) << 1);
                pa[mt][cc] = *(const f16x8*)(p_s + rowp * 64 + bks * 8);
            }

        // PV with V^T b-frags (chunk-swizzled reads — round-7 pair)
        #pragma unroll
        for (int dt = 0; dt < 5; ++dt)
            #pragma unroll
            for (int cc = 0; cc < 2; ++cc) {
                int ck = (cc * 4 + quad) ^ (r & 7);
                f16x8 vbf = *(const f16x8*)(v_s + (dt * 16 + r) * 64 + ck * 8);
                oacc[0][dt] = __builtin_amdgcn_mfma_f32_16x16x32_f16(pa[0][cc], vbf, oacc[0][dt], 0, 0, 0);
                oacc[1][dt] = __builtin_amdgcn_mfma_f32_16x16x32_f16(pa[1][cc], vbf, oacc[1][dt], 0, 0, 0);
            }
    }

    // deferred l reduction (across the 16 r-lanes of each quad)
    float inv_l[2][4];
    #pragma unroll
    for (int mt = 0; mt < 2; ++mt)
        #pragma unroll
        for (int v = 0; v < 4; ++v) {
            float l = l_part[mt][v];
            l += __shfl_xor(l, 1);
            l += __shfl_xor(l, 2);
            l += __shfl_xor(l, 4);
            l += __shfl_xor(l, 8);
            inv_l[mt][v] = 1.0f / l;
        }

    // epilogue: normalize + fp16-split into LDS [128][80] hi/lo, uint4 stores
    __syncthreads();
    #pragma unroll
    for (int mt = 0; mt < 2; ++mt)
        #pragma unroll
        for (int v = 0; v < 4; ++v) {
            int row = wave * 32 + mt * 16 + quad * 4 + v;
            #pragma unroll
            for (int dt = 0; dt < 5; ++dt) {
                float o = oacc[mt][dt][v] * inv_l[mt][v];
                ushort hh, ll;
                splitf16(o, hh, ll);
                lds[row * 80 + dt * 16 + r] = hh;
                lds[10240 + row * 80 + dt * 16 + r] = ll;
            }
        }
    __syncthreads();
    {
        size_t gbase = ((size_t)b * NN + q0) * HIDDEN + h * HD;
        #pragma unroll
        for (int i = 0; i < 10; ++i) {
            int u = tid + i * 256;            // 0..2559
            int plane = u / 1280, idx = u % 1280;
            int row = idx / 10, part = idx % 10;
            uint4 w = *(const uint4*)(lds + plane * 10240 + idx * 8);
            ushort* dst = (plane ? ao_lo : ao_hi) + gbase + (size_t)row * HIDDEN + part * 8;
            *(uint4*)dst = w;
        }
    }
}

// ---------------------------------------------------------------------------
extern "C" void kernel_launch(void* const* d_in, const int* in_sizes, int n_in,
                              void* d_out, int out_size, void* d_ws, size_t ws_size,
                              hipStream_t stream)
{
    const float* x      = (const float*)d_in[0];
    const float* cos_t  = (const float*)d_in[1];
    const float* sin_t  = (const float*)d_in[2];
    const float* qkv_w  = (const float*)d_in[3];
    const float* qkv_b  = (const float*)d_in[4];
    const float* proj_w = (const float*)d_in[5];
    const float* proj_b = (const float*)d_in[6];
    float* out = (float*)d_out;

    char* ws = (char*)d_ws;
    // layout (bytes), phase-based reuse:
    //   [0, 62914560)           qkv fp32 (gemm1 out; dead after rope_split)
    //       -> ao_hi @0 (10485760), ao_lo @10485760 (attn out, fp16 hi/lo)
    //   [62914560, 72744960)    wT fp16 (qkv_w^T); after gemm1:
    //       -> vt fp16 @62914560 (10485760, ends 73400320)
    //       -> re-written by tsplit_f16(proj_w) AFTER attention (3276800)
    //   [82575360, 103546880)   x split fp16 hi/lo (gemm1 A); after gemm1:
    //       -> qf @83886080 (12582912), kf @96468992 (ends 109051904)
    float*  qkv   = (float*)ws;
    ushort* ao_hi = (ushort*)ws;
    ushort* ao_lo = (ushort*)(ws + 10485760);
    ushort* wT    = (ushort*)(ws + 62914560);
    ushort* vt    = (ushort*)(ws + 62914560);
    ushort* a_hi  = (ushort*)(ws + 82575360);
    ushort* a_lo  = (ushort*)(ws + 93061120);
    ushort* q_f   = (ushort*)(ws + 83886080);
    ushort* k_f   = (ushort*)(ws + 96468992);

    // 1) split x into fp16 hi/lo
    split_f16_kernel<<<(MROWS * HIDDEN / 4 + 255) / 256, 256, 0, stream>>>(
        x, a_hi, a_lo, MROWS * HIDDEN / 4);

    // 2) transpose qkv_w -> fp16
    tsplit_f16_kernel<<<dim3(3 * HIDDEN / 32, HIDDEN / 32), 256, 0, stream>>>(
        qkv_w, wT, HIDDEN, 3 * HIDDEN);

    // 3) qkv = x @ qkv_w + qkv_b   (256^2 deep-pipelined fp16x2 MFMA)
    //    grid = (4096/256)*(3840/256) = 16*15 = 240 (divisible by 8 for T1)
    gemm_f16x2_256_kernel<<<dim3((MROWS / 256) * (3 * HIDDEN / 256)), 512, 0, stream>>>(
        a_hi, a_lo, wT, qkv_b, qkv, MROWS, 3 * HIDDEN, HIDDEN, 3 * HIDDEN / 256);

    // 4) RoPE + fp16 relayout (overwrites wT and x-split regions — both dead)
    rope_split_kernel<<<dim3(NN / 64, HEADS, BB), 256, 0, stream>>>(
        qkv, cos_t, sin_t, q_f, k_f, vt);

    // 5) MFMA flash attention (ao overwrites qkv region — dead now)
    attn_mfma_kernel<<<dim3(NN / 128, HEADS, BB), 256, 0, stream>>>(
        q_f, k_f, vt, ao_hi, ao_lo);

    // 6) transpose proj_w -> fp16 (overwrites vt region — dead after attn)
    tsplit_f16_kernel<<<dim3(HIDDEN / 32, HIDDEN / 32), 256, 0, stream>>>(
        proj_w, wT, HIDDEN, HIDDEN);

    // 7) out = attn_out @ proj_w + proj_b   (128^2 fp16x2 MFMA — better grid
    //    coverage at N=1280 than the 256^2 kernel: 320 wgs vs 80)
    gemm_f16x2_kernel<<<dim3(HIDDEN / BN, MROWS / BM), 256, 0, stream>>>(
        ao_hi, ao_lo, wT, proj_b, out, MROWS, HIDDEN, HIDDEN);
}

// Round 2
// 321.639 us; speedup vs baseline: 1.1057x; 1.0096x over previous
//
#include <hip/hip_runtime.h>
#include <hip/hip_bf16.h>
#include <math.h>

#define HIDDEN 1280
#define HEADS 16
#define HD 80           // head dim
#define HALF 40
#define BB 2
#define NN 2048
#define MROWS (BB * NN) // 4096
// 1/sqrt(80) * log2(e): scores come out in log2 domain -> exp2 directly
#define QSCALE ((float)(0.11180339887498949 * 1.4426950408889634))

typedef __attribute__((ext_vector_type(8))) _Float16 f16x8;
typedef __attribute__((ext_vector_type(4))) float f32x4;

#define AS1 __attribute__((address_space(1)))
#define AS3 __attribute__((address_space(3)))

// Split fp32 into fp16 hi + fp16 lo (hi+lo carries ~22 mantissa bits).
__device__ __forceinline__ void splitf16(float x, ushort& hi, ushort& lo) {
    _Float16 h = (_Float16)x;
    _Float16 l = (_Float16)(x - (float)h);
    hi = __builtin_bit_cast(ushort, h);
    lo = __builtin_bit_cast(ushort, l);
}

__device__ __forceinline__ ushort f2h(float x) {
    _Float16 h = (_Float16)x;
    return __builtin_bit_cast(ushort, h);
}

// ---------------------------------------------------------------------------
// Elementwise split: fp32 [n] -> fp16 hi[n], lo[n]. 4 elems/thread.
// ---------------------------------------------------------------------------
__global__ __launch_bounds__(256) void split_f16_kernel(
    const float* __restrict__ in, ushort* __restrict__ hi,
    ushort* __restrict__ lo, int n4)
{
    int i = blockIdx.x * 256 + threadIdx.x;
    if (i >= n4) return;
    float4 v = ((const float4*)in)[i];
    ushort4 h, l;
    splitf16(v.x, h.x, l.x);
    splitf16(v.y, h.y, l.y);
    splitf16(v.z, h.z, l.z);
    splitf16(v.w, h.w, l.w);
    ((ushort4*)hi)[i] = h;
    ((ushort4*)lo)[i] = l;
}

// ---------------------------------------------------------------------------
// Transpose to fp16: W[K][N] fp32 -> WT[N][K] fp16 (single plane).
// ---------------------------------------------------------------------------
__global__ __launch_bounds__(256) void tsplit_f16_kernel(
    const float* __restrict__ W, ushort* __restrict__ T, int K, int N)
{
    __shared__ float s[32][33];
    const int n0 = blockIdx.x * 32;
    const int k0 = blockIdx.y * 32;
    {
        int tn = threadIdx.x & 31, tk = threadIdx.x >> 5;
        #pragma unroll
        for (int i = 0; i < 4; ++i)
            s[tk + i * 8][tn] = W[(size_t)(k0 + tk + i * 8) * N + n0 + tn];
    }
    __syncthreads();
    {
        int tk = threadIdx.x & 31, tn = threadIdx.x >> 5;
        #pragma unroll
        for (int i = 0; i < 4; ++i)
            T[(size_t)(n0 + tn + i * 8) * K + k0 + tk] = f2h(s[tk][tn + i * 8]);
    }
}

// ---------------------------------------------------------------------------
// fp16x2 MFMA GEMM (128x128, 2-barrier structure) — kept for the proj GEMM
// (N=1280: 320 wgs here vs only 80 wgs at 256^2 tiles).
// ---------------------------------------------------------------------------
#define BM 128
#define BN 128
#define BK 32

__global__ __launch_bounds__(256) void gemm_f16x2_kernel(
    const ushort* __restrict__ Ahi, const ushort* __restrict__ Alo,
    const ushort* __restrict__ Bh,
    const float* __restrict__ bias, float* __restrict__ C,
    int M, int N, int K)
{
    __shared__ __align__(16) ushort lds[3 * 128 * 32];   // 24 KB

    const int tid = threadIdx.x;
    const int wid = tid >> 6;
    const int lane = tid & 63;
    const int col0 = blockIdx.x * BN;
    const int row0 = blockIdx.y * BM;
    const int wy = wid >> 1, wx = wid & 1;
    const int lrow = lane >> 2;
    const int lchunk = lane & 3;

    f32x4 acc[4][4] = {};

    for (int k0 = 0; k0 < K; k0 += BK) {
        __syncthreads();
        // 24 segments (3 tiles x 8), 6 per wave
        #pragma unroll
        for (int i = 0; i < 6; ++i) {
            int s = wid + i * 4;
            int tile = s >> 3, t = s & 7;
            const ushort* src = (tile == 0) ? Ahi : (tile == 1) ? Alo : Bh;
            int srow = (tile < 2) ? row0 : col0;
            const ushort* g = src + (size_t)(srow + t * 16 + lrow) * K + k0 + lchunk * 8;
            ushort* l = lds + tile * 4096 + t * 512 + lane * 8;
            __builtin_amdgcn_global_load_lds(
                (const AS1 unsigned int*)g, (AS3 unsigned int*)l, 16, 0, 0);
        }
        __syncthreads();

        const int q = lane >> 4;
        const int r = lane & 15;
        f16x8 ah[4], al[4], bf[4];
        #pragma unroll
        for (int i = 0; i < 4; ++i) {
            int arow = wy * 64 + i * 16 + r;
            ah[i] = *(const f16x8*)(lds + 0 * 4096 + arow * 32 + q * 8);
            al[i] = *(const f16x8*)(lds + 1 * 4096 + arow * 32 + q * 8);
            int brow = wx * 64 + i * 16 + r;
            bf[i] = *(const f16x8*)(lds + 2 * 4096 + brow * 32 + q * 8);
        }
        #pragma unroll
        for (int i = 0; i < 4; ++i) {
            #pragma unroll
            for (int j = 0; j < 4; ++j) {
                acc[i][j] = __builtin_amdgcn_mfma_f32_16x16x32_f16(al[i], bf[j], acc[i][j], 0, 0, 0);
                acc[i][j] = __builtin_amdgcn_mfma_f32_16x16x32_f16(ah[i], bf[j], acc[i][j], 0, 0, 0);
            }
        }
    }

    const int q = lane >> 4, r = lane & 15;
    #pragma unroll
    for (int i = 0; i < 4; ++i) {
        #pragma unroll
        for (int j = 0; j < 4; ++j) {
            int col = col0 + wx * 64 + j * 16 + r;
            float b = bias[col];
            #pragma unroll
            for (int v = 0; v < 4; ++v) {
                int row = row0 + wy * 64 + i * 16 + q * 4 + v;
                C[(size_t)row * N + col] = acc[i][j][v] + b;
            }
        }
    }
}

// ---------------------------------------------------------------------------
// 256x256 8-wave deep-pipelined fp16x2 GEMM (for the QKV GEMM).
// See round-1 notes: T3+T4+T2+T5+T1, 3-buffer LDS ring, counted vmcnt(6).
// ---------------------------------------------------------------------------
__global__ __launch_bounds__(512, 2) void gemm_f16x2_256_kernel(
    const ushort* __restrict__ Ahi, const ushort* __restrict__ Alo,
    const ushort* __restrict__ Bh,
    const float* __restrict__ bias, float* __restrict__ C,
    int M, int N, int K, int nbx)
{
    __shared__ __align__(16) ushort lds[3 * 3 * 8192];   // 144 KB

    const int tid = threadIdx.x;
    const int wid = tid >> 6;
    const int lane = tid & 63;
    const int q = lane >> 4, r = lane & 15;
    const int wr = wid >> 2, wc = wid & 3;

    // T1: XCD-aware block swizzle (valid: grid % 8 == 0)
    int id = blockIdx.x;
    {
        int nwg = gridDim.x;
        if ((nwg & 7) == 0) {
            int c = nwg >> 3;
            id = (id & 7) * c + (id >> 3);
        }
    }
    const int row0 = (id / nbx) * 256;
    const int col0 = (id % nbx) * 256;

    // --- staging addressing: 6 global_load_lds per K-tile per wave ---
    const ushort* gsrc[6];
    int ldst[6];
    #pragma unroll
    for (int j = 0; j < 6; ++j) {
        int pj = j >> 1;
        int rloc = wid * 32 + (j & 1) * 16 + (lane >> 2);
        int sl = (lane & 3) ^ ((rloc >> 1) & 3);
        const ushort* base = (pj == 0) ? Ahi : (pj == 1) ? Alo : Bh;
        int grow = ((pj < 2) ? row0 : col0) + rloc;
        gsrc[j] = base + (size_t)grow * K + sl * 8;
        ldst[j] = pj * 8192 + (wid * 32 + (j & 1) * 16) * 32 + lane * 8;
    }

    const int NT = K / 32;

    // prologue: stage tile 0 -> buf0, tile 1 -> buf1
    #pragma unroll
    for (int j = 0; j < 6; ++j)
        __builtin_amdgcn_global_load_lds((const AS1 unsigned int*)(gsrc[j]),
            (AS3 unsigned int*)(lds + ldst[j]), 16, 0, 0);
    #pragma unroll
    for (int j = 0; j < 6; ++j)
        __builtin_amdgcn_global_load_lds((const AS1 unsigned int*)(gsrc[j] + 32),
            (AS3 unsigned int*)(lds + 24576 + ldst[j]), 16, 0, 0);
    asm volatile("s_waitcnt vmcnt(6)" ::: "memory");   // tile 0 landed, tile 1 in flight
    __builtin_amdgcn_s_barrier();

    const int soff = (q ^ ((r >> 1) & 3)) * 8;
    const int arow0 = wr * 128 + r;     // + m*16
    const int brow0 = wc * 64 + r;      // + n*16

    f32x4 acc[8][4] = {};
    f16x8 ah[4], al[4], bf[4];

    int cb = 0;          // current buffer (tile t)
    int nb = 49152;      // stage target buffer (tile t+2)

    for (int t = 0; t < NT; ++t) {
        const ushort* A0 = lds + cb;
        const ushort* A1 = lds + cb + 8192;
        const ushort* Bp = lds + cb + 16384;
        ushort* nbuf = lds + nb;
        const bool st = (t + 2 < NT);
        const int ko = (t + 2) * 32;

        // ---- phase 1: quadrant (m0-3, n0-1) ----
        #pragma unroll
        for (int m = 0; m < 4; ++m) {
            int ro = (arow0 + m * 16) * 32 + soff;
            ah[m] = *(const f16x8*)(A0 + ro);
            al[m] = *(const f16x8*)(A1 + ro);
        }
        #pragma unroll
        for (int n = 0; n < 2; ++n)
            bf[n] = *(const f16x8*)(Bp + (brow0 + n * 16) * 32 + soff);
        if (st) {
            __builtin_amdgcn_global_load_lds((const AS1 unsigned int*)(gsrc[0] + ko),
                (AS3 unsigned int*)(nbuf + ldst[0]), 16, 0, 0);
            __builtin_amdgcn_global_load_lds((const AS1 unsigned int*)(gsrc[1] + ko),
                (AS3 unsigned int*)(nbuf + ldst[1]), 16, 0, 0);
        }
        __builtin_amdgcn_s_barrier();
        asm volatile("s_waitcnt lgkmcnt(0)" ::: "memory");
        __builtin_amdgcn_sched_barrier(0);
        __builtin_amdgcn_s_setprio(1);
        #pragma unroll
        for (int m = 0; m < 4; ++m) {
            #pragma unroll
            for (int n = 0; n < 2; ++n) {
                acc[m][n] = __builtin_amdgcn_mfma_f32_16x16x32_f16(al[m], bf[n], acc[m][n], 0, 0, 0);
                acc[m][n] = __builtin_amdgcn_mfma_f32_16x16x32_f16(ah[m], bf[n], acc[m][n], 0, 0, 0);
            }
        }
        __builtin_amdgcn_s_setprio(0);
        __builtin_amdgcn_s_barrier();

        // ---- phase 2: quadrant (m0-3, n2-3) ----
        #pragma unroll
        for (int n = 2; n < 4; ++n)
            bf[n] = *(const f16x8*)(Bp + (brow0 + n * 16) * 32 + soff);
        if (st) {
            __builtin_amdgcn_global_load_lds((const AS1 unsigned int*)(gsrc[2] + ko),
                (AS3 unsigned int*)(nbuf + ldst[2]), 16, 0, 0);
            __builtin_amdgcn_global_load_lds((const AS1 unsigned int*)(gsrc[3] + ko),
                (AS3 unsigned int*)(nbuf + ldst[3]), 16, 0, 0);
        }
        __builtin_amdgcn_s_barrier();
        asm volatile("s_waitcnt lgkmcnt(0)" ::: "memory");
        __builtin_amdgcn_sched_barrier(0);
        __builtin_amdgcn_s_setprio(1);
        #pragma unroll
        for (int m = 0; m < 4; ++m) {
            #pragma unroll
            for (int n = 2; n < 4; ++n) {
                acc[m][n] = __builtin_amdgcn_mfma_f32_16x16x32_f16(al[m], bf[n], acc[m][n], 0, 0, 0);
                acc[m][n] = __builtin_amdgcn_mfma_f32_16x16x32_f16(ah[m], bf[n], acc[m][n], 0, 0, 0);
            }
        }
        __builtin_amdgcn_s_setprio(0);
        __builtin_amdgcn_s_barrier();

        // ---- phase 3: quadrant (m4-7, n2-3) ----
        #pragma unroll
        for (int m = 0; m < 4; ++m) {
            int ro = (arow0 + (m + 4) * 16) * 32 + soff;
            ah[m] = *(const f16x8*)(A0 + ro);
            al[m] = *(const f16x8*)(A1 + ro);
        }
        if (st) {
            __builtin_amdgcn_global_load_lds((const AS1 unsigned int*)(gsrc[4] + ko),
                (AS3 unsigned int*)(nbuf + ldst[4]), 16, 0, 0);
            __builtin_amdgcn_global_load_lds((const AS1 unsigned int*)(gsrc[5] + ko),
                (AS3 unsigned int*)(nbuf + ldst[5]), 16, 0, 0);
        }
        __builtin_amdgcn_s_barrier();
        asm volatile("s_waitcnt lgkmcnt(0)" ::: "memory");
        __builtin_amdgcn_sched_barrier(0);
        __builtin_amdgcn_s_setprio(1);
        #pragma unroll
        for (int m = 0; m < 4; ++m) {
            #pragma unroll
            for (int n = 2; n < 4; ++n) {
                acc[m + 4][n] = __builtin_amdgcn_mfma_f32_16x16x32_f16(al[m], bf[n], acc[m + 4][n], 0, 0, 0);
                acc[m + 4][n] = __builtin_amdgcn_mfma_f32_16x16x32_f16(ah[m], bf[n], acc[m + 4][n], 0, 0, 0);
            }
        }
        __builtin_amdgcn_s_setprio(0);
        __builtin_amdgcn_s_barrier();

        // ---- phase 4: quadrant (m4-7, n0-1), register-only ----
        __builtin_amdgcn_s_setprio(1);
        #pragma unroll
        for (int m = 0; m < 4; ++m) {
            #pragma unroll
            for (int n = 0; n < 2; ++n) {
                acc[m + 4][n] = __builtin_amdgcn_mfma_f32_16x16x32_f16(al[m], bf[n], acc[m + 4][n], 0, 0, 0);
                acc[m + 4][n] = __builtin_amdgcn_mfma_f32_16x16x32_f16(ah[m], bf[n], acc[m + 4][n], 0, 0, 0);
            }
        }
        __builtin_amdgcn_s_setprio(0);
        // counted wait: tile t+1's 6 loads retired, tile t+2's 6 stay in flight
        if (st)
            asm volatile("s_waitcnt vmcnt(6)" ::: "memory");
        else if (t + 1 < NT)
            asm volatile("s_waitcnt vmcnt(0)" ::: "memory");
        __builtin_amdgcn_s_barrier();

        cb += 24576; if (cb == 73728) cb = 0;
        nb += 24576; if (nb == 73728) nb = 0;
    }

    // epilogue: bias + store
    #pragma unroll
    for (int m = 0; m < 8; ++m) {
        #pragma unroll
        for (int n = 0; n < 4; ++n) {
            int col = col0 + wc * 64 + n * 16 + r;
            float b = bias[col];
            #pragma unroll
            for (int v = 0; v < 4; ++v) {
                int row = row0 + wr * 128 + m * 16 + q * 4 + v;
                C[(size_t)row * N + col] = acc[m][n][v] + b;
            }
        }
    }
}

// ---------------------------------------------------------------------------
// RoPE + scale + fp16 convert + head-major relayout.
// Reads qkv fp32 (b,n,3,H,80). Writes:
//   qf [bh][n][96] fp16 (RoPE'd, * QSCALE, d 80..95 zeroed)
//   kf [bh][n][96] fp16 (RoPE'd, d 80..95 zeroed)
//   vt [bh][80][2048] fp16 (V transposed)
// Grid (NN/64, HEADS, BB), 256 threads.
// ---------------------------------------------------------------------------
__global__ __launch_bounds__(256) void rope_split_kernel(
    const float* __restrict__ qkv, const float* __restrict__ cos_t,
    const float* __restrict__ sin_t,
    ushort* __restrict__ qf, ushort* __restrict__ kf,
    ushort* __restrict__ vt)
{
    __shared__ float s_v[64][84];
    const int tid = threadIdx.x;
    const int b = blockIdx.z, h = blockIdx.y;
    const int n0 = blockIdx.x * 64;
    const int bh = b * HEADS + h;

    // V tile -> LDS (coalesced float4 loads)
    #pragma unroll
    for (int i = 0; i < 5; ++i) {
        int u = tid + i * 256;
        int n = u / 20, c = u % 20;
        const float* src = qkv + (size_t)(b * NN + n0 + n) * 3840 + 2 * HIDDEN + h * HD + c * 4;
        *(float4*)(&s_v[n][c * 4]) = *(const float4*)src;
    }

    // q,k RoPE + fp16: 640 units, each = (token n, 4-wide d group in [0,40))
    for (int u = tid; u < 640; u += 256) {
        int n = u / 10, p = u % 10;
        int d = p * 4;
        int ng = n0 + n;
        size_t rowb = (size_t)(b * NN + ng) * 3840;
        float4 c0 = *(const float4*)(cos_t + ng * HD + d);
        float4 c1 = *(const float4*)(cos_t + ng * HD + d + HALF);
        float4 s0 = *(const float4*)(sin_t + ng * HD + d);
        float4 s1 = *(const float4*)(sin_t + ng * HD + d + HALF);
        size_t qo = ((size_t)bh * NN + ng) * 96;
        // q (scaled by QSCALE so scores are in log2 domain)
        {
            float4 x0 = *(const float4*)(qkv + rowb + h * HD + d);
            float4 x1 = *(const float4*)(qkv + rowb + h * HD + d + HALF);
            ushort4 h4a, h4b;
            h4a.x = f2h((x0.x * c0.x - x1.x * s0.x) * QSCALE);
            h4a.y = f2h((x0.y * c0.y - x1.y * s0.y) * QSCALE);
            h4a.z = f2h((x0.z * c0.z - x1.z * s0.z) * QSCALE);
            h4a.w = f2h((x0.w * c0.w - x1.w * s0.w) * QSCALE);
            h4b.x = f2h((x1.x * c1.x + x0.x * s1.x) * QSCALE);
            h4b.y = f2h((x1.y * c1.y + x0.y * s1.y) * QSCALE);
            h4b.z = f2h((x1.z * c1.z + x0.z * s1.z) * QSCALE);
            h4b.w = f2h((x1.w * c1.w + x0.w * s1.w) * QSCALE);
            *(ushort4*)(qf + qo + d) = h4a;
            *(ushort4*)(qf + qo + d + HALF) = h4b;
        }
        // k (unscaled)
        {
            float4 x0 = *(const float4*)(qkv + rowb + HIDDEN + h * HD + d);
            float4 x1 = *(const float4*)(qkv + rowb + HIDDEN + h * HD + d + HALF);
            ushort4 h4a, h4b;
            h4a.x = f2h(x0.x * c0.x - x1.x * s0.x);
            h4a.y = f2h(x0.y * c0.y - x1.y * s0.y);
            h4a.z = f2h(x0.z * c0.z - x1.z * s0.z);
            h4a.w = f2h(x0.w * c0.w - x1.w * s0.w);
            h4b.x = f2h(x1.x * c1.x + x0.x * s1.x);
            h4b.y = f2h(x1.y * c1.y + x0.y * s1.y);
            h4b.z = f2h(x1.z * c1.z + x0.z * s1.z);
            h4b.w = f2h(x1.w * c1.w + x0.w * s1.w);
            *(ushort4*)(kf + qo + d) = h4a;
            *(ushort4*)(kf + qo + d + HALF) = h4b;
        }
    }

    // zero the d=80..95 pad for q and k. 256 units: which(1b) x n(6b) x part(1b)
    {
        int which = tid >> 7;
        int u = tid & 127;
        int n = u >> 1, part = u & 1;
        size_t o = ((size_t)bh * NN + n0 + n) * 96 + 80 + part * 8;
        uint4 z = {0u, 0u, 0u, 0u};
        if (which == 0) *(uint4*)(qf + o) = z;
        else            *(uint4*)(kf + o) = z;
    }
    __syncthreads();

    // V^T write (fp16): unit = (d, 16-token chunk)
    for (int u = tid; u < 320; u += 256) {
        int d = u >> 2, nc = u & 3;
        ushort hs[16];
        #pragma unroll
        for (int kk = 0; kk < 16; ++kk)
            hs[kk] = f2h(s_v[nc * 16 + kk][d]);
        size_t o = ((size_t)bh * HD + d) * NN + n0 + nc * 16;
        uint4 w0, w1;
        w0.x = (uint)hs[0] | ((uint)hs[1] << 16);
        w0.y = (uint)hs[2] | ((uint)hs[3] << 16);
        w0.z = (uint)hs[4] | ((uint)hs[5] << 16);
        w0.w = (uint)hs[6] | ((uint)hs[7] << 16);
        w1.x = (uint)hs[8] | ((uint)hs[9] << 16);
        w1.y = (uint)hs[10] | ((uint)hs[11] << 16);
        w1.z = (uint)hs[12] | ((uint)hs[13] << 16);
        w1.w = (uint)hs[14] | ((uint)hs[15] << 16);
        *(uint4*)(vt + o) = w0;
        *(uint4*)(vt + o + 8) = w1;
    }
}

// ---------------------------------------------------------------------------
// MFMA flash attention v5: double-buffered K/V staging (1 barrier/iter,
// staging hidden under compute) + bank-conflict-free K reads.
//  - K tile LDS: [64][128] u16 (16-chunk padded rows), XOR swizzle
//    chunk ^= row&7. Fill: linear global_load_lds dest + inverse-swizzled
//    global source (pad chunks read row-start, never read back).
//  - V tile: [80][64] chunk-swizzled (unchanged round-7 pair).
//  - Per-iter: issue stage(j+1) into other buffer, compute j, vmcnt(0) +
//    one s_barrier. p_s is wave-private (no barrier needed).
//  - setprio(1) around QK and PV MFMA clusters (T5).
// Numerics bit-identical to v4 (same values, same MFMA order).
// LDS: 2*(16K+10K) + 16K p_s = 69632 B -> 2 blocks/CU.
// ---------------------------------------------------------------------------
__global__ __launch_bounds__(256, 2) void attn_mfma_kernel(
    const ushort* __restrict__ qf, const ushort* __restrict__ kf,
    const ushort* __restrict__ vt,
    ushort* __restrict__ ao_hi, ushort* __restrict__ ao_lo)
{
    __shared__ __align__(16) ushort lds[34816];   // 69632 B
    // buf0: [0,13312)   = K0 [64][128] (8192) | V0 [80][64] (5120)
    // buf1: [13312,26624)
    // p_s : [26624,34816) = [128][64]
    _Float16* p_s = (_Float16*)(lds + 26624);

    const int tid = threadIdx.x;
    const int wave = tid >> 6, lane = tid & 63;
    const int quad = lane >> 4, r = lane & 15;
    const int b = blockIdx.z, h = blockIdx.y;
    const int bh = b * HEADS + h;
    const int q0 = blockIdx.x * 128;

    const size_t kb = (size_t)bh * NN * 96;
    const size_t vb = (size_t)bh * HD * NN;

    // ---- staging precompute: seg s = wave + 4*i, i = 0..6 (26 segs) ----
    // K segs (s<16): LDS [64][128], dest off = s*512 + lane*8 (linear).
    //   dest row = s*4 + (lane>>4), chunk t = lane&15; source chunk
    //   g = t ^ (row&7) (clamped to 0 if >=12 — pad slot, never read).
    // V segs (16<=s<26): unchanged round-7 source swizzle.
    const ushort* gptr[7];
    int ldso[7];
    #pragma unroll
    for (int i = 0; i < 7; ++i) {
        int s = wave + i * 4;
        if (s < 16) {
            int row = s * 4 + (lane >> 4);
            int t = lane & 15;
            int g = t ^ (row & 7);
            if (g >= 12) g = 0;
            gptr[i] = kf + kb + (size_t)row * 96 + g * 8;
            ldso[i] = s * 512 + lane * 8;
        } else if (s < 26) {
            int ts = s - 16;
            gptr[i] = vt + vb + (size_t)(ts * 8 + (lane >> 3)) * NN
                      + (size_t)(((lane & 7) ^ (lane >> 3)) * 8);
            ldso[i] = 8192 + ts * 512 + lane * 8;
        } else {
            gptr[i] = nullptr;
            ldso[i] = 0;
        }
    }

    // Q a-frags from [bh][n][96] fp16 (pre-scaled by QSCALE, pad zero)
    f16x8 qfr[2][3];
    #pragma unroll
    for (int mt = 0; mt < 2; ++mt)
        #pragma unroll
        for (int c = 0; c < 3; ++c) {
            size_t o = ((size_t)bh * NN + q0 + wave * 32 + mt * 16 + r) * 96 + c * 32 + quad * 8;
            qfr[mt][c] = *(const f16x8*)(qf + o);
        }

    f32x4 oacc[2][5] = {};
    float l_part[2][4] = {};

    // prologue: stage tile 0 -> buf0
    #pragma unroll
    for (int i = 0; i < 7; ++i) {
        int s = wave + i * 4;
        if (s < 26) {
            __builtin_amdgcn_global_load_lds((const AS1 unsigned int*)gptr[i],
                (AS3 unsigned int*)(lds + ldso[i]), 16, 0, 0);
            gptr[i] += (s < 16) ? 6144 : 64;
        }
    }
    asm volatile("s_waitcnt vmcnt(0)" ::: "memory");
    __builtin_amdgcn_s_barrier();

    int cur = 0;
    for (int j0 = 0; j0 < NN; j0 += 64) {
        const int nxt = 13312 - cur;
        // issue stage(j+1) -> other buffer (free since end of iter j-1)
        if (j0 + 64 < NN) {
            #pragma unroll
            for (int i = 0; i < 7; ++i) {
                int s = wave + i * 4;
                if (s < 26) {
                    __builtin_amdgcn_global_load_lds((const AS1 unsigned int*)gptr[i],
                        (AS3 unsigned int*)(lds + nxt + ldso[i]), 16, 0, 0);
                    gptr[i] += (s < 16) ? 6144 : 64;
                }
            }
        }

        const ushort* k_s = lds + cur;
        const _Float16* v_s = (const _Float16*)(lds + cur + 8192);

        // QK^T -> scores in C-layout (log2 domain), single fp16 term
        // K read: row j (=jt*16+r, j&7 == r&7), chunk (c*4+quad)^(r&7)
        f32x4 sc[2][4] = {};
        __builtin_amdgcn_s_setprio(1);
        #pragma unroll
        for (int jt = 0; jt < 4; ++jt) {
            f16x8 kbf[3];
            int j = jt * 16 + r;
            #pragma unroll
            for (int c = 0; c < 3; ++c) {
                int ch = (c * 4 + quad) ^ (r & 7);
                kbf[c] = *(const f16x8*)(k_s + j * 128 + ch * 8);
            }
            #pragma unroll
            for (int mt = 0; mt < 2; ++mt)
                #pragma unroll
                for (int c = 0; c < 3; ++c)
                    sc[mt][jt] = __builtin_amdgcn_mfma_f32_16x16x32_f16(qfr[mt][c], kbf[c], sc[mt][jt], 0, 0, 0);
        }
        __builtin_amdgcn_s_setprio(0);

        // no-max softmax: p = exp2(s); P -> LDS fp16 (swizzled); l partials
        #pragma unroll
        for (int mt = 0; mt < 2; ++mt) {
            #pragma unroll
            for (int v = 0; v < 4; ++v) {
                float ps = 0.0f;
                #pragma unroll
                for (int jt = 0; jt < 4; ++jt) {
                    float p = __builtin_amdgcn_exp2f(sc[mt][jt][v]);
                    sc[mt][jt][v] = p;
                    ps += p;
                }
                l_part[mt][v] += ps;
            }
            int rowbase = wave * 32 + mt * 16 + quad * 4;
            #pragma unroll
            for (int jt = 0; jt < 4; ++jt) {
                int bks = (jt * 2 + (r >> 3)) ^ (quad << 1);
                #pragma unroll
                for (int v = 0; v < 4; ++v)
                    p_s[(rowbase + v) * 64 + bks * 8 + (r & 7)] = (_Float16)sc[mt][jt][v];
            }
        }

        // P a-frags (wave-private rows, swizzled reads — round-7 pair)
        f16x8 pa[2][2];
        #pragma unroll
        for (int mt = 0; mt < 2; ++mt)
            #pragma unroll
            for (int cc = 0; cc < 2; ++cc) {
                int rowp = wave * 32 + mt * 16 + r;
                int bks = (cc * 4 + quad) ^ (((r >> 2) & 3) << 1);
                pa[mt][cc] = *(const f16x8*)(p_s + rowp * 64 + bks * 8);
            }

        // PV with V^T b-frags (chunk-swizzled reads — round-7 pair)
        __builtin_amdgcn_s_setprio(1);
        #pragma unroll
        for (int dt = 0; dt < 5; ++dt)
            #pragma unroll
            for (int cc = 0; cc < 2; ++cc) {
                int ck = (cc * 4 + quad) ^ (r & 7);
                f16x8 vbf = *(const f16x8*)(v_s + (dt * 16 + r) * 64 + ck * 8);
                oacc[0][dt] = __builtin_amdgcn_mfma_f32_16x16x32_f16(pa[0][cc], vbf, oacc[0][dt], 0, 0, 0);
                oacc[1][dt] = __builtin_amdgcn_mfma_f32_16x16x32_f16(pa[1][cc], vbf, oacc[1][dt], 0, 0, 0);
            }
        __builtin_amdgcn_s_setprio(0);

        // staging for j+1 had the whole compute phase to land; drain + sync
        asm volatile("s_waitcnt vmcnt(0)" ::: "memory");
        __builtin_amdgcn_s_barrier();
        cur = nxt;
    }

    // deferred l reduction (across the 16 r-lanes of each quad)
    float inv_l[2][4];
    #pragma unroll
    for (int mt = 0; mt < 2; ++mt)
        #pragma unroll
        for (int v = 0; v < 4; ++v) {
            float l = l_part[mt][v];
            l += __shfl_xor(l, 1);
            l += __shfl_xor(l, 2);
            l += __shfl_xor(l, 4);
            l += __shfl_xor(l, 8);
            inv_l[mt][v] = 1.0f / l;
        }

    // epilogue: normalize + fp16-split into LDS [128][80] hi/lo, uint4 stores
    __syncthreads();
    #pragma unroll
    for (int mt = 0; mt < 2; ++mt)
        #pragma unroll
        for (int v = 0; v < 4; ++v) {
            int row = wave * 32 + mt * 16 + quad * 4 + v;
            #pragma unroll
            for (int dt = 0; dt < 5; ++dt) {
                float o = oacc[mt][dt][v] * inv_l[mt][v];
                ushort hh, ll;
                splitf16(o, hh, ll);
                lds[row * 80 + dt * 16 + r] = hh;
                lds[10240 + row * 80 + dt * 16 + r] = ll;
            }
        }
    __syncthreads();
    {
        size_t gbase = ((size_t)b * NN + q0) * HIDDEN + h * HD;
        #pragma unroll
        for (int i = 0; i < 10; ++i) {
            int u = tid + i * 256;            // 0..2559
            int plane = u / 1280, idx = u % 1280;
            int row = idx / 10, part = idx % 10;
            uint4 w = *(const uint4*)(lds + plane * 10240 + idx * 8);
            ushort* dst = (plane ? ao_lo : ao_hi) + gbase + (size_t)row * HIDDEN + part * 8;
            *(uint4*)dst = w;
        }
    }
}

// ---------------------------------------------------------------------------
extern "C" void kernel_launch(void* const* d_in, const int* in_sizes, int n_in,
                              void* d_out, int out_size, void* d_ws, size_t ws_size,
                              hipStream_t stream)
{
    const float* x      = (const float*)d_in[0];
    const float* cos_t  = (const float*)d_in[1];
    const float* sin_t  = (const float*)d_in[2];
    const float* qkv_w  = (const float*)d_in[3];
    const float* qkv_b  = (const float*)d_in[4];
    const float* proj_w = (const float*)d_in[5];
    const float* proj_b = (const float*)d_in[6];
    float* out = (float*)d_out;

    char* ws = (char*)d_ws;
    // layout (bytes), phase-based reuse:
    //   [0, 62914560)           qkv fp32 (gemm1 out; dead after rope_split)
    //       -> ao_hi @0 (10485760), ao_lo @10485760 (attn out, fp16 hi/lo)
    //   [62914560, 72744960)    wT fp16 (qkv_w^T); after gemm1:
    //       -> vt fp16 @62914560 (10485760, ends 73400320)
    //       -> re-written by tsplit_f16(proj_w) AFTER attention (3276800)
    //   [82575360, 103546880)   x split fp16 hi/lo (gemm1 A); after gemm1:
    //       -> qf @83886080 (12582912), kf @96468992 (ends 109051904)
    float*  qkv   = (float*)ws;
    ushort* ao_hi = (ushort*)ws;
    ushort* ao_lo = (ushort*)(ws + 10485760);
    ushort* wT    = (ushort*)(ws + 62914560);
    ushort* vt    = (ushort*)(ws + 62914560);
    ushort* a_hi  = (ushort*)(ws + 82575360);
    ushort* a_lo  = (ushort*)(ws + 93061120);
    ushort* q_f   = (ushort*)(ws + 83886080);
    ushort* k_f   = (ushort*)(ws + 96468992);

    // 1) split x into fp16 hi/lo
    split_f16_kernel<<<(MROWS * HIDDEN / 4 + 255) / 256, 256, 0, stream>>>(
        x, a_hi, a_lo, MROWS * HIDDEN / 4);

    // 2) transpose qkv_w -> fp16
    tsplit_f16_kernel<<<dim3(3 * HIDDEN / 32, HIDDEN / 32), 256, 0, stream>>>(
        qkv_w, wT, HIDDEN, 3 * HIDDEN);

    // 3) qkv = x @ qkv_w + qkv_b   (256^2 deep-pipelined fp16x2 MFMA)
    gemm_f16x2_256_kernel<<<dim3((MROWS / 256) * (3 * HIDDEN / 256)), 512, 0, stream>>>(
        a_hi, a_lo, wT, qkv_b, qkv, MROWS, 3 * HIDDEN, HIDDEN, 3 * HIDDEN / 256);

    // 4) RoPE + fp16 relayout (overwrites wT and x-split regions — both dead)
    rope_split_kernel<<<dim3(NN / 64, HEADS, BB), 256, 0, stream>>>(
        qkv, cos_t, sin_t, q_f, k_f, vt);

    // 5) MFMA flash attention (ao overwrites qkv region — dead now)
    attn_mfma_kernel<<<dim3(NN / 128, HEADS, BB), 256, 0, stream>>>(
        q_f, k_f, vt, ao_hi, ao_lo);

    // 6) transpose proj_w -> fp16 (overwrites vt region — dead after attn)
    tsplit_f16_kernel<<<dim3(HIDDEN / 32, HIDDEN / 32), 256, 0, stream>>>(
        proj_w, wT, HIDDEN, HIDDEN);

    // 7) out = attn_out @ proj_w + proj_b   (128^2 fp16x2 MFMA — better grid
    //    coverage at N=1280 than the 256^2 kernel: 320 wgs vs 80)
    gemm_f16x2_kernel<<<dim3(HIDDEN / BN, MROWS / BM), 256, 0, stream>>>(
        ao_hi, ao_lo, wT, proj_b, out, MROWS, HIDDEN, HIDDEN);
}

// Round 3
// 318.149 us; speedup vs baseline: 1.1178x; 1.0110x over previous
//
#include <hip/hip_runtime.h>
#include <hip/hip_bf16.h>
#include <math.h>

#define HIDDEN 1280
#define HEADS 16
#define HD 80           // head dim
#define HALF 40
#define BB 2
#define NN 2048
#define MROWS (BB * NN) // 4096
// 1/sqrt(80) * log2(e): scores come out in log2 domain -> exp2 directly
#define QSCALE ((float)(0.11180339887498949 * 1.4426950408889634))

typedef __attribute__((ext_vector_type(8))) _Float16 f16x8;
typedef __attribute__((ext_vector_type(4))) float f32x4;

#define AS1 __attribute__((address_space(1)))
#define AS3 __attribute__((address_space(3)))

// Split fp32 into fp16 hi + fp16 lo (hi+lo carries ~22 mantissa bits).
__device__ __forceinline__ void splitf16(float x, ushort& hi, ushort& lo) {
    _Float16 h = (_Float16)x;
    _Float16 l = (_Float16)(x - (float)h);
    hi = __builtin_bit_cast(ushort, h);
    lo = __builtin_bit_cast(ushort, l);
}

__device__ __forceinline__ ushort f2h(float x) {
    _Float16 h = (_Float16)x;
    return __builtin_bit_cast(ushort, h);
}

// ---------------------------------------------------------------------------
// Elementwise split: fp32 [n] -> fp16 hi[n], lo[n]. 4 elems/thread.
// ---------------------------------------------------------------------------
__global__ __launch_bounds__(256) void split_f16_kernel(
    const float* __restrict__ in, ushort* __restrict__ hi,
    ushort* __restrict__ lo, int n4)
{
    int i = blockIdx.x * 256 + threadIdx.x;
    if (i >= n4) return;
    float4 v = ((const float4*)in)[i];
    ushort4 h, l;
    splitf16(v.x, h.x, l.x);
    splitf16(v.y, h.y, l.y);
    splitf16(v.z, h.z, l.z);
    splitf16(v.w, h.w, l.w);
    ((ushort4*)hi)[i] = h;
    ((ushort4*)lo)[i] = l;
}

// ---------------------------------------------------------------------------
// Transpose to fp16: W[K][N] fp32 -> WT[N][K] fp16 (single plane).
// ---------------------------------------------------------------------------
__global__ __launch_bounds__(256) void tsplit_f16_kernel(
    const float* __restrict__ W, ushort* __restrict__ T, int K, int N)
{
    __shared__ float s[32][33];
    const int n0 = blockIdx.x * 32;
    const int k0 = blockIdx.y * 32;
    {
        int tn = threadIdx.x & 31, tk = threadIdx.x >> 5;
        #pragma unroll
        for (int i = 0; i < 4; ++i)
            s[tk + i * 8][tn] = W[(size_t)(k0 + tk + i * 8) * N + n0 + tn];
    }
    __syncthreads();
    {
        int tk = threadIdx.x & 31, tn = threadIdx.x >> 5;
        #pragma unroll
        for (int i = 0; i < 4; ++i)
            T[(size_t)(n0 + tn + i * 8) * K + k0 + tk] = f2h(s[tk][tn + i * 8]);
    }
}

// ---------------------------------------------------------------------------
// fp16x2 MFMA GEMM (128x128, 2-barrier structure) — kept for the proj GEMM
// (N=1280: 320 wgs here vs only 80 wgs at 256^2 tiles).
// ---------------------------------------------------------------------------
#define BM 128
#define BN 128
#define BK 32

__global__ __launch_bounds__(256) void gemm_f16x2_kernel(
    const ushort* __restrict__ Ahi, const ushort* __restrict__ Alo,
    const ushort* __restrict__ Bh,
    const float* __restrict__ bias, float* __restrict__ C,
    int M, int N, int K)
{
    __shared__ __align__(16) ushort lds[3 * 128 * 32];   // 24 KB

    const int tid = threadIdx.x;
    const int wid = tid >> 6;
    const int lane = tid & 63;
    const int col0 = blockIdx.x * BN;
    const int row0 = blockIdx.y * BM;
    const int wy = wid >> 1, wx = wid & 1;
    const int lrow = lane >> 2;
    const int lchunk = lane & 3;

    f32x4 acc[4][4] = {};

    for (int k0 = 0; k0 < K; k0 += BK) {
        __syncthreads();
        // 24 segments (3 tiles x 8), 6 per wave
        #pragma unroll
        for (int i = 0; i < 6; ++i) {
            int s = wid + i * 4;
            int tile = s >> 3, t = s & 7;
            const ushort* src = (tile == 0) ? Ahi : (tile == 1) ? Alo : Bh;
            int srow = (tile < 2) ? row0 : col0;
            const ushort* g = src + (size_t)(srow + t * 16 + lrow) * K + k0 + lchunk * 8;
            ushort* l = lds + tile * 4096 + t * 512 + lane * 8;
            __builtin_amdgcn_global_load_lds(
                (const AS1 unsigned int*)g, (AS3 unsigned int*)l, 16, 0, 0);
        }
        __syncthreads();

        const int q = lane >> 4;
        const int r = lane & 15;
        f16x8 ah[4], al[4], bf[4];
        #pragma unroll
        for (int i = 0; i < 4; ++i) {
            int arow = wy * 64 + i * 16 + r;
            ah[i] = *(const f16x8*)(lds + 0 * 4096 + arow * 32 + q * 8);
            al[i] = *(const f16x8*)(lds + 1 * 4096 + arow * 32 + q * 8);
            int brow = wx * 64 + i * 16 + r;
            bf[i] = *(const f16x8*)(lds + 2 * 4096 + brow * 32 + q * 8);
        }
        #pragma unroll
        for (int i = 0; i < 4; ++i) {
            #pragma unroll
            for (int j = 0; j < 4; ++j) {
                acc[i][j] = __builtin_amdgcn_mfma_f32_16x16x32_f16(al[i], bf[j], acc[i][j], 0, 0, 0);
                acc[i][j] = __builtin_amdgcn_mfma_f32_16x16x32_f16(ah[i], bf[j], acc[i][j], 0, 0, 0);
            }
        }
    }

    const int q = lane >> 4, r = lane & 15;
    #pragma unroll
    for (int i = 0; i < 4; ++i) {
        #pragma unroll
        for (int j = 0; j < 4; ++j) {
            int col = col0 + wx * 64 + j * 16 + r;
            float b = bias[col];
            #pragma unroll
            for (int v = 0; v < 4; ++v) {
                int row = row0 + wy * 64 + i * 16 + q * 4 + v;
                C[(size_t)row * N + col] = acc[i][j][v] + b;
            }
        }
    }
}

// ---------------------------------------------------------------------------
// 256x256 8-wave deep-pipelined fp16x2 GEMM (for the QKV GEMM).
// T3+T4+T2+T5+T1, 3-buffer LDS ring, counted vmcnt(6).
// ---------------------------------------------------------------------------
__global__ __launch_bounds__(512, 2) void gemm_f16x2_256_kernel(
    const ushort* __restrict__ Ahi, const ushort* __restrict__ Alo,
    const ushort* __restrict__ Bh,
    const float* __restrict__ bias, float* __restrict__ C,
    int M, int N, int K, int nbx)
{
    __shared__ __align__(16) ushort lds[3 * 3 * 8192];   // 144 KB

    const int tid = threadIdx.x;
    const int wid = tid >> 6;
    const int lane = tid & 63;
    const int q = lane >> 4, r = lane & 15;
    const int wr = wid >> 2, wc = wid & 3;

    // T1: XCD-aware block swizzle (valid: grid % 8 == 0)
    int id = blockIdx.x;
    {
        int nwg = gridDim.x;
        if ((nwg & 7) == 0) {
            int c = nwg >> 3;
            id = (id & 7) * c + (id >> 3);
        }
    }
    const int row0 = (id / nbx) * 256;
    const int col0 = (id % nbx) * 256;

    // --- staging addressing: 6 global_load_lds per K-tile per wave ---
    const ushort* gsrc[6];
    int ldst[6];
    #pragma unroll
    for (int j = 0; j < 6; ++j) {
        int pj = j >> 1;
        int rloc = wid * 32 + (j & 1) * 16 + (lane >> 2);
        int sl = (lane & 3) ^ ((rloc >> 1) & 3);
        const ushort* base = (pj == 0) ? Ahi : (pj == 1) ? Alo : Bh;
        int grow = ((pj < 2) ? row0 : col0) + rloc;
        gsrc[j] = base + (size_t)grow * K + sl * 8;
        ldst[j] = pj * 8192 + (wid * 32 + (j & 1) * 16) * 32 + lane * 8;
    }

    const int NT = K / 32;

    // prologue: stage tile 0 -> buf0, tile 1 -> buf1
    #pragma unroll
    for (int j = 0; j < 6; ++j)
        __builtin_amdgcn_global_load_lds((const AS1 unsigned int*)(gsrc[j]),
            (AS3 unsigned int*)(lds + ldst[j]), 16, 0, 0);
    #pragma unroll
    for (int j = 0; j < 6; ++j)
        __builtin_amdgcn_global_load_lds((const AS1 unsigned int*)(gsrc[j] + 32),
            (AS3 unsigned int*)(lds + 24576 + ldst[j]), 16, 0, 0);
    asm volatile("s_waitcnt vmcnt(6)" ::: "memory");   // tile 0 landed, tile 1 in flight
    __builtin_amdgcn_s_barrier();

    const int soff = (q ^ ((r >> 1) & 3)) * 8;
    const int arow0 = wr * 128 + r;     // + m*16
    const int brow0 = wc * 64 + r;      // + n*16

    f32x4 acc[8][4] = {};
    f16x8 ah[4], al[4], bf[4];

    int cb = 0;          // current buffer (tile t)
    int nb = 49152;      // stage target buffer (tile t+2)

    for (int t = 0; t < NT; ++t) {
        const ushort* A0 = lds + cb;
        const ushort* A1 = lds + cb + 8192;
        const ushort* Bp = lds + cb + 16384;
        ushort* nbuf = lds + nb;
        const bool st = (t + 2 < NT);
        const int ko = (t + 2) * 32;

        // ---- phase 1: quadrant (m0-3, n0-1) ----
        #pragma unroll
        for (int m = 0; m < 4; ++m) {
            int ro = (arow0 + m * 16) * 32 + soff;
            ah[m] = *(const f16x8*)(A0 + ro);
            al[m] = *(const f16x8*)(A1 + ro);
        }
        #pragma unroll
        for (int n = 0; n < 2; ++n)
            bf[n] = *(const f16x8*)(Bp + (brow0 + n * 16) * 32 + soff);
        if (st) {
            __builtin_amdgcn_global_load_lds((const AS1 unsigned int*)(gsrc[0] + ko),
                (AS3 unsigned int*)(nbuf + ldst[0]), 16, 0, 0);
            __builtin_amdgcn_global_load_lds((const AS1 unsigned int*)(gsrc[1] + ko),
                (AS3 unsigned int*)(nbuf + ldst[1]), 16, 0, 0);
        }
        __builtin_amdgcn_s_barrier();
        asm volatile("s_waitcnt lgkmcnt(0)" ::: "memory");
        __builtin_amdgcn_sched_barrier(0);
        __builtin_amdgcn_s_setprio(1);
        #pragma unroll
        for (int m = 0; m < 4; ++m) {
            #pragma unroll
            for (int n = 0; n < 2; ++n) {
                acc[m][n] = __builtin_amdgcn_mfma_f32_16x16x32_f16(al[m], bf[n], acc[m][n], 0, 0, 0);
                acc[m][n] = __builtin_amdgcn_mfma_f32_16x16x32_f16(ah[m], bf[n], acc[m][n], 0, 0, 0);
            }
        }
        __builtin_amdgcn_s_setprio(0);
        __builtin_amdgcn_s_barrier();

        // ---- phase 2: quadrant (m0-3, n2-3) ----
        #pragma unroll
        for (int n = 2; n < 4; ++n)
            bf[n] = *(const f16x8*)(Bp + (brow0 + n * 16) * 32 + soff);
        if (st) {
            __builtin_amdgcn_global_load_lds((const AS1 unsigned int*)(gsrc[2] + ko),
                (AS3 unsigned int*)(nbuf + ldst[2]), 16, 0, 0);
            __builtin_amdgcn_global_load_lds((const AS1 unsigned int*)(gsrc[3] + ko),
                (AS3 unsigned int*)(nbuf + ldst[3]), 16, 0, 0);
        }
        __builtin_amdgcn_s_barrier();
        asm volatile("s_waitcnt lgkmcnt(0)" ::: "memory");
        __builtin_amdgcn_sched_barrier(0);
        __builtin_amdgcn_s_setprio(1);
        #pragma unroll
        for (int m = 0; m < 4; ++m) {
            #pragma unroll
            for (int n = 2; n < 4; ++n) {
                acc[m][n] = __builtin_amdgcn_mfma_f32_16x16x32_f16(al[m], bf[n], acc[m][n], 0, 0, 0);
                acc[m][n] = __builtin_amdgcn_mfma_f32_16x16x32_f16(ah[m], bf[n], acc[m][n], 0, 0, 0);
            }
        }
        __builtin_amdgcn_s_setprio(0);
        __builtin_amdgcn_s_barrier();

        // ---- phase 3: quadrant (m4-7, n2-3) ----
        #pragma unroll
        for (int m = 0; m < 4; ++m) {
            int ro = (arow0 + (m + 4) * 16) * 32 + soff;
            ah[m] = *(const f16x8*)(A0 + ro);
            al[m] = *(const f16x8*)(A1 + ro);
        }
        if (st) {
            __builtin_amdgcn_global_load_lds((const AS1 unsigned int*)(gsrc[4] + ko),
                (AS3 unsigned int*)(nbuf + ldst[4]), 16, 0, 0);
            __builtin_amdgcn_global_load_lds((const AS1 unsigned int*)(gsrc[5] + ko),
                (AS3 unsigned int*)(nbuf + ldst[5]), 16, 0, 0);
        }
        __builtin_amdgcn_s_barrier();
        asm volatile("s_waitcnt lgkmcnt(0)" ::: "memory");
        __builtin_amdgcn_sched_barrier(0);
        __builtin_amdgcn_s_setprio(1);
        #pragma unroll
        for (int m = 0; m < 4; ++m) {
            #pragma unroll
            for (int n = 2; n < 4; ++n) {
                acc[m + 4][n] = __builtin_amdgcn_mfma_f32_16x16x32_f16(al[m], bf[n], acc[m + 4][n], 0, 0, 0);
                acc[m + 4][n] = __builtin_amdgcn_mfma_f32_16x16x32_f16(ah[m], bf[n], acc[m + 4][n], 0, 0, 0);
            }
        }
        __builtin_amdgcn_s_setprio(0);
        __builtin_amdgcn_s_barrier();

        // ---- phase 4: quadrant (m4-7, n0-1), register-only ----
        __builtin_amdgcn_s_setprio(1);
        #pragma unroll
        for (int m = 0; m < 4; ++m) {
            #pragma unroll
            for (int n = 0; n < 2; ++n) {
                acc[m + 4][n] = __builtin_amdgcn_mfma_f32_16x16x32_f16(al[m], bf[n], acc[m + 4][n], 0, 0, 0);
                acc[m + 4][n] = __builtin_amdgcn_mfma_f32_16x16x32_f16(ah[m], bf[n], acc[m + 4][n], 0, 0, 0);
            }
        }
        __builtin_amdgcn_s_setprio(0);
        // counted wait: tile t+1's 6 loads retired, tile t+2's 6 stay in flight
        if (st)
            asm volatile("s_waitcnt vmcnt(6)" ::: "memory");
        else if (t + 1 < NT)
            asm volatile("s_waitcnt vmcnt(0)" ::: "memory");
        __builtin_amdgcn_s_barrier();

        cb += 24576; if (cb == 73728) cb = 0;
        nb += 24576; if (nb == 73728) nb = 0;
    }

    // epilogue: bias + store
    #pragma unroll
    for (int m = 0; m < 8; ++m) {
        #pragma unroll
        for (int n = 0; n < 4; ++n) {
            int col = col0 + wc * 64 + n * 16 + r;
            float b = bias[col];
            #pragma unroll
            for (int v = 0; v < 4; ++v) {
                int row = row0 + wr * 128 + m * 16 + q * 4 + v;
                C[(size_t)row * N + col] = acc[m][n][v] + b;
            }
        }
    }
}

// ---------------------------------------------------------------------------
// RoPE + scale + fp16 convert + head-major relayout.
// Reads qkv fp32 (b,n,3,H,80). Writes:
//   qf [bh][n][96] fp16 (RoPE'd, * QSCALE, d 80..95 zeroed)
//   kf [bh][n][96] fp16 (RoPE'd, d 80..95 zeroed)
//   vt [bh][80][2048] fp16 (V transposed)
// Grid (NN/64, HEADS, BB), 256 threads.
// ---------------------------------------------------------------------------
__global__ __launch_bounds__(256) void rope_split_kernel(
    const float* __restrict__ qkv, const float* __restrict__ cos_t,
    const float* __restrict__ sin_t,
    ushort* __restrict__ qf, ushort* __restrict__ kf,
    ushort* __restrict__ vt)
{
    __shared__ float s_v[64][84];
    const int tid = threadIdx.x;
    const int b = blockIdx.z, h = blockIdx.y;
    const int n0 = blockIdx.x * 64;
    const int bh = b * HEADS + h;

    // V tile -> LDS (coalesced float4 loads)
    #pragma unroll
    for (int i = 0; i < 5; ++i) {
        int u = tid + i * 256;
        int n = u / 20, c = u % 20;
        const float* src = qkv + (size_t)(b * NN + n0 + n) * 3840 + 2 * HIDDEN + h * HD + c * 4;
        *(float4*)(&s_v[n][c * 4]) = *(const float4*)src;
    }

    // q,k RoPE + fp16: 640 units, each = (token n, 4-wide d group in [0,40))
    for (int u = tid; u < 640; u += 256) {
        int n = u / 10, p = u % 10;
        int d = p * 4;
        int ng = n0 + n;
        size_t rowb = (size_t)(b * NN + ng) * 3840;
        float4 c0 = *(const float4*)(cos_t + ng * HD + d);
        float4 c1 = *(const float4*)(cos_t + ng * HD + d + HALF);
        float4 s0 = *(const float4*)(sin_t + ng * HD + d);
        float4 s1 = *(const float4*)(sin_t + ng * HD + d + HALF);
        size_t qo = ((size_t)bh * NN + ng) * 96;
        // q (scaled by QSCALE so scores are in log2 domain)
        {
            float4 x0 = *(const float4*)(qkv + rowb + h * HD + d);
            float4 x1 = *(const float4*)(qkv + rowb + h * HD + d + HALF);
            ushort4 h4a, h4b;
            h4a.x = f2h((x0.x * c0.x - x1.x * s0.x) * QSCALE);
            h4a.y = f2h((x0.y * c0.y - x1.y * s0.y) * QSCALE);
            h4a.z = f2h((x0.z * c0.z - x1.z * s0.z) * QSCALE);
            h4a.w = f2h((x0.w * c0.w - x1.w * s0.w) * QSCALE);
            h4b.x = f2h((x1.x * c1.x + x0.x * s1.x) * QSCALE);
            h4b.y = f2h((x1.y * c1.y + x0.y * s1.y) * QSCALE);
            h4b.z = f2h((x1.z * c1.z + x0.z * s1.z) * QSCALE);
            h4b.w = f2h((x1.w * c1.w + x0.w * s1.w) * QSCALE);
            *(ushort4*)(qf + qo + d) = h4a;
            *(ushort4*)(qf + qo + d + HALF) = h4b;
        }
        // k (unscaled)
        {
            float4 x0 = *(const float4*)(qkv + rowb + HIDDEN + h * HD + d);
            float4 x1 = *(const float4*)(qkv + rowb + HIDDEN + h * HD + d + HALF);
            ushort4 h4a, h4b;
            h4a.x = f2h(x0.x * c0.x - x1.x * s0.x);
            h4a.y = f2h(x0.y * c0.y - x1.y * s0.y);
            h4a.z = f2h(x0.z * c0.z - x1.z * s0.z);
            h4a.w = f2h(x0.w * c0.w - x1.w * s0.w);
            h4b.x = f2h(x1.x * c1.x + x0.x * s1.x);
            h4b.y = f2h(x1.y * c1.y + x0.y * s1.y);
            h4b.z = f2h(x1.z * c1.z + x0.z * s1.z);
            h4b.w = f2h(x1.w * c1.w + x0.w * s1.w);
            *(ushort4*)(kf + qo + d) = h4a;
            *(ushort4*)(kf + qo + d + HALF) = h4b;
        }
    }

    // zero the d=80..95 pad for q and k. 256 units: which(1b) x n(6b) x part(1b)
    {
        int which = tid >> 7;
        int u = tid & 127;
        int n = u >> 1, part = u & 1;
        size_t o = ((size_t)bh * NN + n0 + n) * 96 + 80 + part * 8;
        uint4 z = {0u, 0u, 0u, 0u};
        if (which == 0) *(uint4*)(qf + o) = z;
        else            *(uint4*)(kf + o) = z;
    }
    __syncthreads();

    // V^T write (fp16): unit = (d, 16-token chunk)
    for (int u = tid; u < 320; u += 256) {
        int d = u >> 2, nc = u & 3;
        ushort hs[16];
        #pragma unroll
        for (int kk = 0; kk < 16; ++kk)
            hs[kk] = f2h(s_v[nc * 16 + kk][d]);
        size_t o = ((size_t)bh * HD + d) * NN + n0 + nc * 16;
        uint4 w0, w1;
        w0.x = (uint)hs[0] | ((uint)hs[1] << 16);
        w0.y = (uint)hs[2] | ((uint)hs[3] << 16);
        w0.z = (uint)hs[4] | ((uint)hs[5] << 16);
        w0.w = (uint)hs[6] | ((uint)hs[7] << 16);
        w1.x = (uint)hs[8] | ((uint)hs[9] << 16);
        w1.y = (uint)hs[10] | ((uint)hs[11] << 16);
        w1.z = (uint)hs[12] | ((uint)hs[13] << 16);
        w1.w = (uint)hs[14] | ((uint)hs[15] << 16);
        *(uint4*)(vt + o) = w0;
        *(uint4*)(vt + o + 8) = w1;
    }
}

// ---------------------------------------------------------------------------
// MFMA flash attention v6: 8 waves (512 thr), wave = 16 Q-rows.
// Same math/order as v5 (bit-identical): the old per-wave mt∈{0,1} halves
// are now separate waves (wave_new = 2*wave_old + mt). Double-buffered K/V
// staging (26 segs over 8 waves), K [64][128] XOR-swizzled, V chunk-swizzled,
// p_s [128][64] rows = wave*16.. (wave-private). 69632 B LDS -> 2 blocks/CU
// = 16 waves/CU = 4 waves/SIMD (v5 was 2/SIMD: latency-exposed).
// ---------------------------------------------------------------------------
__global__ __launch_bounds__(512, 4) void attn_mfma_kernel(
    const ushort* __restrict__ qf, const ushort* __restrict__ kf,
    const ushort* __restrict__ vt,
    ushort* __restrict__ ao_hi, ushort* __restrict__ ao_lo)
{
    __shared__ __align__(16) ushort lds[34816];   // 69632 B
    // buf0: [0,13312)   = K0 [64][128] (8192) | V0 [80][64] (5120)
    // buf1: [13312,26624)
    // p_s : [26624,34816) = [128][64]
    _Float16* p_s = (_Float16*)(lds + 26624);

    const int tid = threadIdx.x;
    const int wave = tid >> 6, lane = tid & 63;
    const int quad = lane >> 4, r = lane & 15;
    const int b = blockIdx.z, h = blockIdx.y;
    const int bh = b * HEADS + h;
    const int q0 = blockIdx.x * 128;

    const size_t kb = (size_t)bh * NN * 96;
    const size_t vb = (size_t)bh * HD * NN;

    // ---- staging precompute: seg s = wave + 8*i, i = 0..3 (26 segs) ----
    // K segs (s<16): LDS [64][128]; dest row = s*4 + (lane>>4), chunk t =
    //   lane&15; source chunk g = t ^ (row&7) (clamped to 0 if >=12 — pad
    //   slot, never read back).
    // V segs (16<=s<26): round-7 source swizzle (unchanged).
    const ushort* gptr[4];
    int ldso[4];
    #pragma unroll
    for (int i = 0; i < 4; ++i) {
        int s = wave + i * 8;
        if (s < 16) {
            int row = s * 4 + (lane >> 4);
            int t = lane & 15;
            int g = t ^ (row & 7);
            if (g >= 12) g = 0;
            gptr[i] = kf + kb + (size_t)row * 96 + g * 8;
            ldso[i] = s * 512 + lane * 8;
        } else if (s < 26) {
            int ts = s - 16;
            gptr[i] = vt + vb + (size_t)(ts * 8 + (lane >> 3)) * NN
                      + (size_t)(((lane & 7) ^ (lane >> 3)) * 8);
            ldso[i] = 8192 + ts * 512 + lane * 8;
        } else {
            gptr[i] = nullptr;
            ldso[i] = 0;
        }
    }

    // Q a-frags from [bh][n][96] fp16 (pre-scaled by QSCALE, pad zero)
    f16x8 qfr[3];
    #pragma unroll
    for (int c = 0; c < 3; ++c) {
        size_t o = ((size_t)bh * NN + q0 + wave * 16 + r) * 96 + c * 32 + quad * 8;
        qfr[c] = *(const f16x8*)(qf + o);
    }

    f32x4 oacc[5] = {};
    float l_part[4] = {};

    // prologue: stage tile 0 -> buf0
    #pragma unroll
    for (int i = 0; i < 4; ++i) {
        int s = wave + i * 8;
        if (s < 26) {
            __builtin_amdgcn_global_load_lds((const AS1 unsigned int*)gptr[i],
                (AS3 unsigned int*)(lds + ldso[i]), 16, 0, 0);
            gptr[i] += (s < 16) ? 6144 : 64;
        }
    }
    asm volatile("s_waitcnt vmcnt(0)" ::: "memory");
    __builtin_amdgcn_s_barrier();

    int cur = 0;
    for (int j0 = 0; j0 < NN; j0 += 64) {
        const int nxt = 13312 - cur;
        // issue stage(j+1) -> other buffer (free since end of iter j-1)
        if (j0 + 64 < NN) {
            #pragma unroll
            for (int i = 0; i < 4; ++i) {
                int s = wave + i * 8;
                if (s < 26) {
                    __builtin_amdgcn_global_load_lds((const AS1 unsigned int*)gptr[i],
                        (AS3 unsigned int*)(lds + nxt + ldso[i]), 16, 0, 0);
                    gptr[i] += (s < 16) ? 6144 : 64;
                }
            }
        }

        const ushort* k_s = lds + cur;
        const _Float16* v_s = (const _Float16*)(lds + cur + 8192);

        // QK^T -> scores in C-layout (log2 domain), single fp16 term
        // K read: row j (=jt*16+r, j&7 == r&7), chunk (c*4+quad)^(r&7)
        f32x4 sc[4] = {};
        __builtin_amdgcn_s_setprio(1);
        #pragma unroll
        for (int jt = 0; jt < 4; ++jt) {
            f16x8 kbf[3];
            int j = jt * 16 + r;
            #pragma unroll
            for (int c = 0; c < 3; ++c) {
                int ch = (c * 4 + quad) ^ (r & 7);
                kbf[c] = *(const f16x8*)(k_s + j * 128 + ch * 8);
            }
            #pragma unroll
            for (int c = 0; c < 3; ++c)
                sc[jt] = __builtin_amdgcn_mfma_f32_16x16x32_f16(qfr[c], kbf[c], sc[jt], 0, 0, 0);
        }
        __builtin_amdgcn_s_setprio(0);

        // no-max softmax: p = exp2(s); P -> LDS fp16 (swizzled); l partials
        #pragma unroll
        for (int v = 0; v < 4; ++v) {
            float ps = 0.0f;
            #pragma unroll
            for (int jt = 0; jt < 4; ++jt) {
                float p = __builtin_amdgcn_exp2f(sc[jt][v]);
                sc[jt][v] = p;
                ps += p;
            }
            l_part[v] += ps;
        }
        {
            int rowbase = wave * 16 + quad * 4;
            #pragma unroll
            for (int jt = 0; jt < 4; ++jt) {
                int bks = (jt * 2 + (r >> 3)) ^ (quad << 1);
                #pragma unroll
                for (int v = 0; v < 4; ++v)
                    p_s[(rowbase + v) * 64 + bks * 8 + (r & 7)] = (_Float16)sc[jt][v];
            }
        }

        // P a-frags (wave-private rows, swizzled reads — round-7 pair)
        f16x8 pa[2];
        #pragma unroll
        for (int cc = 0; cc < 2; ++cc) {
            int rowp = wave * 16 + r;
            int bks = (cc * 4 + quad) ^ (((r >> 2) & 3) << 1);
            pa[cc] = *(const f16x8*)(p_s + rowp * 64 + bks * 8);
        }

        // PV with V^T b-frags (chunk-swizzled reads — round-7 pair)
        __builtin_amdgcn_s_setprio(1);
        #pragma unroll
        for (int dt = 0; dt < 5; ++dt)
            #pragma unroll
            for (int cc = 0; cc < 2; ++cc) {
                int ck = (cc * 4 + quad) ^ (r & 7);
                f16x8 vbf = *(const f16x8*)(v_s + (dt * 16 + r) * 64 + ck * 8);
                oacc[dt] = __builtin_amdgcn_mfma_f32_16x16x32_f16(pa[cc], vbf, oacc[dt], 0, 0, 0);
            }
        __builtin_amdgcn_s_setprio(0);

        // staging for j+1 had the whole compute phase to land; drain + sync
        asm volatile("s_waitcnt vmcnt(0)" ::: "memory");
        __builtin_amdgcn_s_barrier();
        cur = nxt;
    }

    // deferred l reduction (across the 16 r-lanes of each quad)
    float inv_l[4];
    #pragma unroll
    for (int v = 0; v < 4; ++v) {
        float l = l_part[v];
        l += __shfl_xor(l, 1);
        l += __shfl_xor(l, 2);
        l += __shfl_xor(l, 4);
        l += __shfl_xor(l, 8);
        inv_l[v] = 1.0f / l;
    }

    // epilogue: normalize + fp16-split into LDS [128][80] hi/lo, uint4 stores
    __syncthreads();
    #pragma unroll
    for (int v = 0; v < 4; ++v) {
        int row = wave * 16 + quad * 4 + v;
        #pragma unroll
        for (int dt = 0; dt < 5; ++dt) {
            float o = oacc[dt][v] * inv_l[v];
            ushort hh, ll;
            splitf16(o, hh, ll);
            lds[row * 80 + dt * 16 + r] = hh;
            lds[10240 + row * 80 + dt * 16 + r] = ll;
        }
    }
    __syncthreads();
    {
        size_t gbase = ((size_t)b * NN + q0) * HIDDEN + h * HD;
        #pragma unroll
        for (int i = 0; i < 5; ++i) {
            int u = tid + i * 512;            // 0..2559
            int plane = u / 1280, idx = u % 1280;
            int row = idx / 10, part = idx % 10;
            uint4 w = *(const uint4*)(lds + plane * 10240 + idx * 8);
            ushort* dst = (plane ? ao_lo : ao_hi) + gbase + (size_t)row * HIDDEN + part * 8;
            *(uint4*)dst = w;
        }
    }
}

// ---------------------------------------------------------------------------
extern "C" void kernel_launch(void* const* d_in, const int* in_sizes, int n_in,
                              void* d_out, int out_size, void* d_ws, size_t ws_size,
                              hipStream_t stream)
{
    const float* x      = (const float*)d_in[0];
    const float* cos_t  = (const float*)d_in[1];
    const float* sin_t  = (const float*)d_in[2];
    const float* qkv_w  = (const float*)d_in[3];
    const float* qkv_b  = (const float*)d_in[4];
    const float* proj_w = (const float*)d_in[5];
    const float* proj_b = (const float*)d_in[6];
    float* out = (float*)d_out;

    char* ws = (char*)d_ws;
    // layout (bytes), phase-based reuse:
    //   [0, 62914560)           qkv fp32 (gemm1 out; dead after rope_split)
    //       -> ao_hi @0 (10485760), ao_lo @10485760 (attn out, fp16 hi/lo)
    //   [62914560, 72744960)    wT fp16 (qkv_w^T); after gemm1:
    //       -> vt fp16 @62914560 (10485760, ends 73400320)
    //       -> re-written by tsplit_f16(proj_w) AFTER attention (3276800)
    //   [82575360, 103546880)   x split fp16 hi/lo (gemm1 A); after gemm1:
    //       -> qf @83886080 (12582912), kf @96468992 (ends 109051904)
    float*  qkv   = (float*)ws;
    ushort* ao_hi = (ushort*)ws;
    ushort* ao_lo = (ushort*)(ws + 10485760);
    ushort* wT    = (ushort*)(ws + 62914560);
    ushort* vt    = (ushort*)(ws + 62914560);
    ushort* a_hi  = (ushort*)(ws + 82575360);
    ushort* a_lo  = (ushort*)(ws + 93061120);
    ushort* q_f   = (ushort*)(ws + 83886080);
    ushort* k_f   = (ushort*)(ws + 96468992);

    // 1) split x into fp16 hi/lo
    split_f16_kernel<<<(MROWS * HIDDEN / 4 + 255) / 256, 256, 0, stream>>>(
        x, a_hi, a_lo, MROWS * HIDDEN / 4);

    // 2) transpose qkv_w -> fp16
    tsplit_f16_kernel<<<dim3(3 * HIDDEN / 32, HIDDEN / 32), 256, 0, stream>>>(
        qkv_w, wT, HIDDEN, 3 * HIDDEN);

    // 3) qkv = x @ qkv_w + qkv_b   (256^2 deep-pipelined fp16x2 MFMA)
    gemm_f16x2_256_kernel<<<dim3((MROWS / 256) * (3 * HIDDEN / 256)), 512, 0, stream>>>(
        a_hi, a_lo, wT, qkv_b, qkv, MROWS, 3 * HIDDEN, HIDDEN, 3 * HIDDEN / 256);

    // 4) RoPE + fp16 relayout (overwrites wT and x-split regions — both dead)
    rope_split_kernel<<<dim3(NN / 64, HEADS, BB), 256, 0, stream>>>(
        qkv, cos_t, sin_t, q_f, k_f, vt);

    // 5) MFMA flash attention v6 (8 waves, ao overwrites qkv region — dead now)
    attn_mfma_kernel<<<dim3(NN / 128, HEADS, BB), 512, 0, stream>>>(
        q_f, k_f, vt, ao_hi, ao_lo);

    // 6) transpose proj_w -> fp16 (overwrites vt region — dead after attn)
    tsplit_f16_kernel<<<dim3(HIDDEN / 32, HIDDEN / 32), 256, 0, stream>>>(
        proj_w, wT, HIDDEN, HIDDEN);

    // 7) out = attn_out @ proj_w + proj_b   (128^2 fp16x2 MFMA — better grid
    //    coverage at N=1280 than the 256^2 kernel: 320 wgs vs 80)
    gemm_f16x2_kernel<<<dim3(HIDDEN / BN, MROWS / BM), 256, 0, stream>>>(
        ao_hi, ao_lo, wT, proj_b, out, MROWS, HIDDEN, HIDDEN);
}